// Round 8
// baseline (227.116 us; speedup 1.0000x reference)
//
#include <hip/hip_runtime.h>
#include <cstdint>

// ---------- types & helpers ----------
typedef __attribute__((ext_vector_type(8))) short short8_t;
typedef __attribute__((ext_vector_type(8))) __bf16 bf16x8_t;
typedef __attribute__((ext_vector_type(4))) float f32x4_t;

__device__ __forceinline__ float bf2f(unsigned short u) {
  return __uint_as_float(((unsigned)u) << 16);
}
__device__ __forceinline__ unsigned short f2bf(float f) {  // RNE
  unsigned u = __float_as_uint(f);
  u += 0x7FFFu + ((u >> 16) & 1u);
  return (unsigned short)(u >> 16);
}
__device__ __forceinline__ unsigned short f2bf_rhu(float f) {  // round-half-up (hot loops)
  return (unsigned short)((__float_as_uint(f) + 0x8000u) >> 16);
}

// MFMA wrapper: tolerate either builtin signature (short8 or bf16x8 operands).
template <typename V>
__device__ __forceinline__ auto mfma16_impl(V a, V b, f32x4_t c, int)
    -> decltype(__builtin_amdgcn_mfma_f32_16x16x32_bf16(a, b, c, 0, 0, 0)) {
  return __builtin_amdgcn_mfma_f32_16x16x32_bf16(a, b, c, 0, 0, 0);
}
template <typename V>
__device__ __forceinline__ f32x4_t mfma16_impl(V a, V b, f32x4_t c, long) {
  bf16x8_t ab = __builtin_bit_cast(bf16x8_t, a);
  bf16x8_t bb = __builtin_bit_cast(bf16x8_t, b);
  return __builtin_amdgcn_mfma_f32_16x16x32_bf16(ab, bb, c, 0, 0, 0);
}
__device__ __forceinline__ f32x4_t MFMA16(short8_t a, short8_t b, f32x4_t c) {
  return mfma16_impl(a, b, c, 0);
}

#define KPITCH 72   // 64-col K-tiles padded to 72 (rows land 2 lanes/bank = free)
#define SPITCH 136  // 128-col tiles (k_scores)

#define FRAG_VARS                                                       \
  const int tid = threadIdx.x;                                          \
  const int lane = tid & 63;                                            \
  const int wv = tid >> 6;                                              \
  const int mw = (wv >> 1) << 5;                                        \
  const int nw = (wv & 1) << 5;                                         \
  const int fr = lane & 15;                                             \
  const int fq = lane >> 4;                                             \
  f32x4_t acc00 = {0.f, 0.f, 0.f, 0.f};                                 \
  f32x4_t acc01 = acc00, acc10 = acc00, acc11 = acc00;

// Body sees: ml (local m), nl (local n), vv (float value). Variadic for commas.
#define GEMM_EPILOGUE(...)                                              \
  {                                                                     \
    const f32x4_t accs_[4] = {acc00, acc01, acc10, acc11};              \
    _Pragma("unroll") for (int im_ = 0; im_ < 2; ++im_)                 \
    _Pragma("unroll") for (int jn_ = 0; jn_ < 2; ++jn_) {               \
      f32x4_t aa_ = accs_[im_ * 2 + jn_];                               \
      const int ml0_ = mw + im_ * 16 + fq * 4;                          \
      const int nl = nw + jn_ * 16 + fr;                                \
      _Pragma("unroll") for (int r_ = 0; r_ < 4; ++r_) {                \
        const int ml = ml0_ + r_;                                       \
        const float vv = aa_[r_];                                       \
        __VA_ARGS__;                                                    \
      }                                                                 \
    }                                                                   \
  }

// MFMA group for one 32-wide k-slice read from KPITCH LDS tiles.
#define MFMA_K32(aLbuf, bLbuf, kf)                                      \
  do {                                                                  \
    short8_t a0_ = *(const short8_t*)&aLbuf[(mw + fr) * KPITCH + (kf)]; \
    short8_t a1_ = *(const short8_t*)&aLbuf[(mw + 16 + fr) * KPITCH + (kf)]; \
    short8_t b0_ = *(const short8_t*)&bLbuf[(nw + fr) * KPITCH + (kf)]; \
    short8_t b1_ = *(const short8_t*)&bLbuf[(nw + 16 + fr) * KPITCH + (kf)]; \
    acc00 = MFMA16(a0_, b0_, acc00);                                    \
    acc01 = MFMA16(a0_, b1_, acc01);                                    \
    acc10 = MFMA16(a1_, b0_, acc10);                                    \
    acc11 = MFMA16(a1_, b1_, acc11);                                    \
  } while (0)

// bf16x8 (short8) * scalar f32 -> bf16x8
__device__ __forceinline__ short8_t prods8(short8_t t, float s) {
  union { short8_t v; unsigned short u[8]; } in, r;
  in.v = t;
#pragma unroll
  for (int j = 0; j < 8; ++j) r.u[j] = f2bf_rhu(bf2f(in.u[j]) * s);
  return r.v;
}

// ---------- inline dtype detector (per-block, deterministic, L2-broadcast) ----------
// Call with all 256 threads; contains __syncthreads.
__device__ __forceinline__ int detect_f32(const void* q, int tid, int* sh) {
  const unsigned short* p = (const unsigned short*)q;
  int w = 0;
  for (int i = tid; i < 512; i += 256) {
    float v = bf2f(p[i]);
    float av = fabsf(v);
    if (!(av <= 1e4f) || (v != 0.f && av < 1e-10f)) ++w;  // NaN fails av<=1e4
  }
#pragma unroll
  for (int off = 32; off > 0; off >>= 1) w += __shfl_xor(w, off);
  if ((tid & 63) == 0) sh[tid >> 6] = w;
  __syncthreads();
  return (sh[0] + sh[1] + sh[2] + sh[3]) > 40;  // 1 = inputs are f32
}

__device__ __forceinline__ unsigned short load_as_bf16(const void* p, size_t i, int f32mode) {
  return f32mode ? f2bf(((const float*)p)[i]) : ((const unsigned short*)p)[i];
}

// ---------- merged prep: convert (z<9) + weight transpose (z>=9), flag inline ----------
struct PrepArgs {
  const void* csrc[9];
  unsigned short* cdst[9];
  int cn[9];
  const void* tsrc[6];
  unsigned short* tdst[6];
  int tK[6];
};

__global__ __launch_bounds__(256) void k_prep(PrepArgs a) {
  __shared__ int shw[4];
  __shared__ unsigned short t[32][33];
  const int f32mode = detect_f32(a.csrc[0], threadIdx.x, shw);
  const int z = blockIdx.z;
  if (z < 9) {
    const int n = a.cn[z];
    const int bid = blockIdx.y * 16 + blockIdx.x;  // 0..767
    const int stride = 768 * 256;
    for (int i = bid * 256 + threadIdx.x; i < n; i += stride)
      a.cdst[z][i] = load_as_bf16(a.csrc[z], i, f32mode);
  } else {
    const int w = z - 9;
    const int K = a.tK[w];
    const int k0 = blockIdx.y * 32, n0 = blockIdx.x * 32;
    if (k0 >= K) return;
    const int tx = threadIdx.x & 31, ty = threadIdx.x >> 5;
    const void* s = a.tsrc[w];
#pragma unroll
    for (int i = 0; i < 4; ++i)
      t[ty + i * 8][tx] = load_as_bf16(s, (size_t)(k0 + ty + i * 8) * 512 + n0 + tx, f32mode);
    __syncthreads();
    unsigned short* d = a.tdst[w];
#pragma unroll
    for (int i = 0; i < 4; ++i)
      d[(size_t)(n0 + ty + i * 8) * K + k0 + tx] = t[tx][ty + i * 8];
  }
}

// ---------- five projections: K-step 64, small-LDS, compact 768-block grid ----------
struct ProjArgs {
  const unsigned short* A[5];
  const unsigned short* W[5];
  const unsigned short* bias[5];
  unsigned short* out[5];
};

__global__ __launch_bounds__(256) void k_proj(ProjArgs args) {
  const int id = blockIdx.x;  // 0..767, all live
  int op, by, bx;
  if (id < 256) {
    op = 0; by = id >> 3; bx = id & 7;
  } else {
    int r = id - 256;
    op = 1 + (r >> 7); r &= 127; by = r >> 3; bx = r & 7;
  }
  const int m0 = by * 64, n0 = bx * 64;
  const unsigned short* A = args.A[op];
  const unsigned short* W = args.W[op];
  FRAG_VARS;
  __shared__ __align__(16) unsigned short aL[64 * KPITCH];
  __shared__ __align__(16) unsigned short bL[64 * KPITCH];
  const int r = tid >> 3, c = (tid & 7) * 8;  // rows 0..31; +32 for second slot
  for (int k0 = 0; k0 < 1024; k0 += 64) {
    uint4 a0v = *(const uint4*)&A[(size_t)(m0 + r) * 1024 + k0 + c];
    uint4 a1v = *(const uint4*)&A[(size_t)(m0 + r + 32) * 1024 + k0 + c];
    uint4 b0v = *(const uint4*)&W[(size_t)(n0 + r) * 1024 + k0 + c];
    uint4 b1v = *(const uint4*)&W[(size_t)(n0 + r + 32) * 1024 + k0 + c];
    __syncthreads();
    *(uint4*)&aL[r * KPITCH + c] = a0v;
    *(uint4*)&aL[(r + 32) * KPITCH + c] = a1v;
    *(uint4*)&bL[r * KPITCH + c] = b0v;
    *(uint4*)&bL[(r + 32) * KPITCH + c] = b1v;
    __syncthreads();
    MFMA_K32(aL, bL, fq * 8);
    MFMA_K32(aL, bL, 32 + fq * 8);
  }
  const float scale = (op == 0) ? 0.044194173824159216f : 1.0f;
  const unsigned short* bias = args.bias[op];
  unsigned short* out = args.out[op];
  GEMM_EPILOGUE({
    const float v = (vv + bf2f(bias[n0 + nl])) * scale;
    const int m = m0 + ml;
    const int n = n0 + nl;
    if (op < 3) {
      out[(size_t)m * 512 + n] = f2bf(v);
    } else {
      const int bb = m >> 6;
      const int ss = m & 63;
      out[(size_t)bb * 32768 + (size_t)n * 64 + ss] = f2bf(v);
    }
  });
}

// ---------- scores: reuse-heavy LDS-staged (R5 known-good) ----------
__global__ __launch_bounds__(256) void k_scores(
    const unsigned short* __restrict__ qs, const unsigned short* __restrict__ skey,
    const unsigned short* __restrict__ tkey, unsigned short* __restrict__ scores) {
  const int b = blockIdx.z;
  const int m0 = blockIdx.y * 64;
  const int sx = blockIdx.x;  // s = sx*2 + {0,1}
  const int tid = threadIdx.x;
  const int lane = tid & 63;
  const int wv = tid >> 6;
  const int mw = (wv >> 1) << 5;
  const int nw = (wv & 1) << 5;
  const int fr = lane & 15;
  const int fq = lane >> 4;
  __shared__ __align__(16) unsigned short qL[64 * SPITCH];
  __shared__ __align__(16) unsigned short tkL[64 * SPITCH];
  __shared__ __align__(16) unsigned short skL[2 * SPITCH];
  f32x4_t acc[2][4];
#pragma unroll
  for (int s = 0; s < 2; ++s)
#pragma unroll
    for (int i = 0; i < 4; ++i) acc[s][i] = (f32x4_t){0.f, 0.f, 0.f, 0.f};
  const unsigned short* qb = qs + ((size_t)b * 128 + m0) * 512;
  const unsigned short* tkb = tkey + (size_t)b * 64 * 512;
  const unsigned short* skb = skey + ((size_t)b * 64 + sx * 2) * 512;
  for (int kc = 0; kc < 4; ++kc) {
    const int kbase = kc * 128;
    __syncthreads();
#pragma unroll
    for (int i = 0; i < 4; ++i) {
      const int u = tid + i * 256;
      const int r = u >> 4, c = (u & 15) * 8;
      *(uint4*)&qL[r * SPITCH + c] = *(const uint4*)&qb[(size_t)r * 512 + kbase + c];
      *(uint4*)&tkL[r * SPITCH + c] = *(const uint4*)&tkb[(size_t)r * 512 + kbase + c];
    }
    if (tid < 32) {
      const int r = tid >> 4, c = (tid & 15) * 8;
      *(uint4*)&skL[r * SPITCH + c] = *(const uint4*)&skb[(size_t)r * 512 + kbase + c];
    }
    __syncthreads();
#pragma unroll
    for (int ks = 0; ks < 4; ++ks) {
      const int kf = ks * 32 + fq * 8;
      short8_t a0 = *(const short8_t*)&qL[(mw + fr) * SPITCH + kf];
      short8_t a1 = *(const short8_t*)&qL[(mw + 16 + fr) * SPITCH + kf];
      uint4 tq[2];
      tq[0] = *(const uint4*)&tkL[(nw + fr) * SPITCH + kf];
      tq[1] = *(const uint4*)&tkL[(nw + 16 + fr) * SPITCH + kf];
      float tlo[2][4], thi[2][4];
#pragma unroll
      for (int h = 0; h < 2; ++h) {
        const unsigned* tw = (const unsigned*)&tq[h];
#pragma unroll
        for (int j = 0; j < 4; ++j) {
          tlo[h][j] = __uint_as_float(tw[j] << 16);
          thi[h][j] = __uint_as_float(tw[j] & 0xffff0000u);
        }
      }
#pragma unroll
      for (int s = 0; s < 2; ++s) {
        uint4 skq = *(const uint4*)&skL[s * SPITCH + kf];
        const unsigned* sw = (const unsigned*)&skq;
        union { short8_t v; unsigned w[4]; } b0, b1;
#pragma unroll
        for (int j = 0; j < 4; ++j) {
          const float slo = __uint_as_float(sw[j] << 16);
          const float shi = __uint_as_float(sw[j] & 0xffff0000u);
          b0.w[j] = __builtin_amdgcn_perm(__float_as_uint(thi[0][j] * shi),
                                          __float_as_uint(tlo[0][j] * slo), 0x07060302);
          b1.w[j] = __builtin_amdgcn_perm(__float_as_uint(thi[1][j] * shi),
                                          __float_as_uint(tlo[1][j] * slo), 0x07060302);
        }
        acc[s][0] = MFMA16(a0, b0.v, acc[s][0]);
        acc[s][1] = MFMA16(a0, b1.v, acc[s][1]);
        acc[s][2] = MFMA16(a1, b0.v, acc[s][2]);
        acc[s][3] = MFMA16(a1, b1.v, acc[s][3]);
      }
    }
  }
#pragma unroll
  for (int s = 0; s < 2; ++s) {
    unsigned short* out = scores + ((size_t)b * 128 + m0) * 4096 + (size_t)(sx * 2 + s) * 64;
#pragma unroll
    for (int im = 0; im < 2; ++im)
#pragma unroll
      for (int jn = 0; jn < 2; ++jn) {
        f32x4_t aa = acc[s][im * 2 + jn];
        const int col = nw + jn * 16 + fr;
#pragma unroll
        for (int r = 0; r < 4; ++r) {
          const int row = mw + im * 16 + fq * 4 + r;
          out[(size_t)row * 4096 + col] = f2bf(aa[r]);
        }
      }
  }
}

// ---------- in-place softmax over each row of 4096 ----------
__global__ __launch_bounds__(256) void k_softmax(unsigned short* __restrict__ s) {
  unsigned short* p = s + (size_t)blockIdx.x * 4096;
  const int t = threadIdx.x;
  union U8 { uint4 q; unsigned short u[8]; };
  U8 a, b;
  a.q = *(const uint4*)&p[t * 16];
  b.q = *(const uint4*)&p[t * 16 + 8];
  float x[16];
#pragma unroll
  for (int j = 0; j < 8; ++j) { x[j] = bf2f(a.u[j]); x[8 + j] = bf2f(b.u[j]); }
  float m = x[0];
#pragma unroll
  for (int j = 1; j < 16; ++j) m = fmaxf(m, x[j]);
  for (int off = 32; off > 0; off >>= 1) m = fmaxf(m, __shfl_xor(m, off));
  __shared__ float redm[4], reds[4];
  if ((t & 63) == 0) redm[t >> 6] = m;
  __syncthreads();
  m = fmaxf(fmaxf(redm[0], redm[1]), fmaxf(redm[2], redm[3]));
  float sum = 0.f;
#pragma unroll
  for (int j = 0; j < 16; ++j) { x[j] = __expf(x[j] - m); sum += x[j]; }
  for (int off = 32; off > 0; off >>= 1) sum += __shfl_xor(sum, off);
  if ((t & 63) == 0) reds[t >> 6] = sum;
  __syncthreads();
  sum = reds[0] + reds[1] + reds[2] + reds[3];
  const float inv = 1.0f / sum;
#pragma unroll
  for (int j = 0; j < 8; ++j) {
    a.u[j] = f2bf(x[j] * inv);
    b.u[j] = f2bf(x[8 + j] * inv);
  }
  *(uint4*)&p[t * 16] = a.q;
  *(uint4*)&p[t * 16 + 8] = b.q;
}

// ---------- ctx partials: split-K x4 over s; bf16 partials (R5 known-good) ----------
__global__ __launch_bounds__(256) void k_ctx(
    const unsigned short* __restrict__ p, const unsigned short* __restrict__ svT,
    const unsigned short* __restrict__ tvT, unsigned short* __restrict__ part) {
  const int b = blockIdx.x >> 1;
  const int m0 = (blockIdx.x & 1) * 64;
  const int n0 = blockIdx.y * 64;
  const int z = blockIdx.z;
  FRAG_VARS;
  __shared__ __align__(16) unsigned short tvl[64 * 72];
  __shared__ __align__(16) unsigned short svl[64 * 24];
  {
    const unsigned short* tvb = tvT + (size_t)b * 32768 + (size_t)n0 * 64;
    const unsigned short* svb = svT + (size_t)b * 32768 + (size_t)n0 * 64 + z * 16;
#pragma unroll
    for (int it = 0; it < 2; ++it) {
      const int idx = tid + it * 256;
      const int r = idx >> 3, c = (idx & 7) * 8;
      *(uint4*)&tvl[r * 72 + c] = *(const uint4*)&tvb[(size_t)r * 64 + c];
    }
    if (tid < 128) {
      const int r = tid >> 1, c = (tid & 1) * 8;
      *(uint4*)&svl[r * 24 + c] = *(const uint4*)&svb[(size_t)r * 64 + c];
    }
  }
  __syncthreads();
  const unsigned short* ar0 =
      p + ((size_t)b * 128 + m0 + mw + fr) * 4096 + z * 1024 + fq * 8;
  const unsigned short* ar1 = ar0 + (size_t)16 * 4096;
  uint4 pa0[4], pa1[4];
#pragma unroll
  for (int i = 0; i < 4; ++i) {
    pa0[i] = *(const uint4*)(ar0 + i * 32);
    pa1[i] = *(const uint4*)(ar1 + i * 32);
  }
#pragma unroll 4
  for (int ks = 0; ks < 32; ++ks) {
    const int sl = ks & 3;
    short8_t av0 = __builtin_bit_cast(short8_t, pa0[sl]);
    short8_t av1 = __builtin_bit_cast(short8_t, pa1[sl]);
    const int kn = ks + 4;
    if (kn < 32) {
      pa0[sl] = *(const uint4*)(ar0 + kn * 32);
      pa1[sl] = *(const uint4*)(ar1 + kn * 32);
    }
    const int s_l = ks >> 1;
    const int t0 = (ks & 1) * 32;
    short8_t tv0 = *(const short8_t*)&tvl[(nw + fr) * 72 + t0 + fq * 8];
    short8_t tv1 = *(const short8_t*)&tvl[(nw + 16 + fr) * 72 + t0 + fq * 8];
    const float sv0 = bf2f(svl[(nw + fr) * 24 + s_l]);
    const float sv1 = bf2f(svl[(nw + 16 + fr) * 24 + s_l]);
    short8_t bv0 = prods8(tv0, sv0);
    short8_t bv1 = prods8(tv1, sv1);
    acc00 = MFMA16(av0, bv0, acc00);
    acc01 = MFMA16(av0, bv1, acc01);
    acc10 = MFMA16(av1, bv0, acc10);
    acc11 = MFMA16(av1, bv1, acc11);
  }
  unsigned short* out = part + ((size_t)z * 2048 + (size_t)b * 128 + m0) * 512 + n0;
  GEMM_EPILOGUE({ out[(size_t)ml * 512 + nl] = f2bf(vv); });
}

// ---------- out = relu(concat(query, sum_z part) @ Wo + bo); K=64, reduce fused ----------
__global__ __launch_bounds__(256) void k_out(
    const unsigned short* __restrict__ query, const unsigned short* __restrict__ part,
    const unsigned short* __restrict__ WoT, const unsigned short* __restrict__ bo,
    void* __restrict__ outv, const void* __restrict__ rawq) {
  __shared__ int shw[4];
  const int f32mode = detect_f32(rawq, threadIdx.x, shw);
  const int m0 = blockIdx.y * 64, n0 = blockIdx.x * 64;
  FRAG_VARS;
  __shared__ __align__(16) unsigned short aL[64 * KPITCH];
  __shared__ __align__(16) unsigned short bL[64 * KPITCH];
  const int r = tid >> 3, c = (tid & 7) * 8;
  const size_t N = (size_t)2048 * 512;
  for (int k0 = 0; k0 < 1536; k0 += 64) {
    uint4 a0v, a1v;
    if (k0 < 1024) {
      a0v = *(const uint4*)&query[(size_t)(m0 + r) * 1024 + k0 + c];
      a1v = *(const uint4*)&query[(size_t)(m0 + r + 32) * 1024 + k0 + c];
    } else {
      const int kk = k0 - 1024;
      float s0[8], s1[8];
#pragma unroll
      for (int j = 0; j < 8; ++j) { s0[j] = 0.f; s1[j] = 0.f; }
#pragma unroll
      for (int z = 0; z < 4; ++z) {
        union { uint4 q; unsigned short u[8]; } t0, t1;
        t0.q = *(const uint4*)&part[z * N + (size_t)(m0 + r) * 512 + kk + c];
        t1.q = *(const uint4*)&part[z * N + (size_t)(m0 + r + 32) * 512 + kk + c];
#pragma unroll
        for (int j = 0; j < 8; ++j) { s0[j] += bf2f(t0.u[j]); s1[j] += bf2f(t1.u[j]); }
      }
      union { uint4 q; unsigned short u[8]; } o0, o1;
#pragma unroll
      for (int j = 0; j < 8; ++j) { o0.u[j] = f2bf(s0[j]); o1.u[j] = f2bf(s1[j]); }
      a0v = o0.q; a1v = o1.q;
    }
    uint4 b0v = *(const uint4*)&WoT[(size_t)(n0 + r) * 1536 + k0 + c];
    uint4 b1v = *(const uint4*)&WoT[(size_t)(n0 + r + 32) * 1536 + k0 + c];
    __syncthreads();
    *(uint4*)&aL[r * KPITCH + c] = a0v;
    *(uint4*)&aL[(r + 32) * KPITCH + c] = a1v;
    *(uint4*)&bL[r * KPITCH + c] = b0v;
    *(uint4*)&bL[(r + 32) * KPITCH + c] = b1v;
    __syncthreads();
    MFMA_K32(aL, bL, fq * 8);
    MFMA_K32(aL, bL, 32 + fq * 8);
  }
  GEMM_EPILOGUE({
    float v = fmaxf(vv + bf2f(bo[n0 + nl]), 0.f);
    const size_t idx = (size_t)(m0 + ml) * 512 + n0 + nl;
    if (f32mode)
      ((float*)outv)[idx] = v;
    else
      ((unsigned short*)outv)[idx] = f2bf(v);
  });
}

// ---------- launch ----------
extern "C" void kernel_launch(void* const* d_in, const int* in_sizes, int n_in,
                              void* d_out, int out_size, void* d_ws, size_t ws_size,
                              hipStream_t stream) {
  const void* query = d_in[0];
  const void* src = d_in[1];
  const void* trg = d_in[2];
  const void* Wq = d_in[3];
  const void* bq = d_in[4];
  const void* Ws = d_in[5];
  const void* bs = d_in[6];
  const void* Wt = d_in[7];
  const void* bt = d_in[8];
  const void* Wsv = d_in[9];
  const void* bsv = d_in[10];
  const void* Wtv = d_in[11];
  const void* btv = d_in[12];
  const void* Wo = d_in[13];
  const void* bo = d_in[14];

  char* ws = (char*)d_ws;
  size_t off = 0;
  auto alloc = [&](size_t bytes) {
    char* ptr = ws + off;
    off = (off + bytes + 255) & ~(size_t)255;
    return ptr;
  };
  unsigned short* qc = (unsigned short*)alloc((size_t)2048 * 1024 * 2);
  unsigned short* srcc = (unsigned short*)alloc((size_t)1024 * 1024 * 2);
  unsigned short* trgc = (unsigned short*)alloc((size_t)1024 * 1024 * 2);
  unsigned short* biasc = (unsigned short*)alloc((size_t)6 * 512 * 2);
  unsigned short* wT = (unsigned short*)alloc((size_t)5 * 524288 * 2);
  unsigned short* woT = (unsigned short*)alloc((size_t)512 * 1536 * 2);
  unsigned short* q_s = (unsigned short*)alloc((size_t)2048 * 512 * 2);
  unsigned short* s_key = (unsigned short*)alloc((size_t)1024 * 512 * 2);
  unsigned short* t_key = (unsigned short*)alloc((size_t)1024 * 512 * 2);
  unsigned short* sv_T = (unsigned short*)alloc((size_t)16 * 512 * 64 * 2);
  unsigned short* tv_T = (unsigned short*)alloc((size_t)16 * 512 * 64 * 2);
  unsigned short* scores = (unsigned short*)alloc((size_t)2048 * 4096 * 2);
  unsigned short* part = (unsigned short*)alloc((size_t)4 * 2048 * 512 * 2);
  (void)ws_size; (void)in_sizes; (void)n_in; (void)out_size;

  PrepArgs pr;
  pr.csrc[0] = query; pr.csrc[1] = src; pr.csrc[2] = trg;
  pr.csrc[3] = bq; pr.csrc[4] = bs; pr.csrc[5] = bt;
  pr.csrc[6] = bsv; pr.csrc[7] = btv; pr.csrc[8] = bo;
  pr.cdst[0] = qc; pr.cdst[1] = srcc; pr.cdst[2] = trgc;
  for (int i = 0; i < 6; ++i) pr.cdst[3 + i] = biasc + i * 512;
  pr.cn[0] = 2048 * 1024; pr.cn[1] = 1024 * 1024; pr.cn[2] = 1024 * 1024;
  for (int i = 0; i < 6; ++i) pr.cn[3 + i] = 512;
  pr.tsrc[0] = Wq; pr.tsrc[1] = Ws; pr.tsrc[2] = Wt;
  pr.tsrc[3] = Wsv; pr.tsrc[4] = Wtv; pr.tsrc[5] = Wo;
  for (int i = 0; i < 5; ++i) { pr.tdst[i] = wT + (size_t)i * 524288; pr.tK[i] = 1024; }
  pr.tdst[5] = woT; pr.tK[5] = 1536;
  hipLaunchKernelGGL(k_prep, dim3(16, 48, 15), dim3(256), 0, stream, pr);

  ProjArgs pa;
  pa.A[0] = qc; pa.A[1] = srcc; pa.A[2] = trgc; pa.A[3] = srcc; pa.A[4] = trgc;
  for (int i = 0; i < 5; ++i) pa.W[i] = wT + (size_t)i * 524288;
  for (int i = 0; i < 5; ++i) pa.bias[i] = biasc + i * 512;
  pa.out[0] = q_s; pa.out[1] = s_key; pa.out[2] = t_key; pa.out[3] = sv_T; pa.out[4] = tv_T;
  hipLaunchKernelGGL(k_proj, dim3(768), dim3(256), 0, stream, pa);

  hipLaunchKernelGGL(k_scores, dim3(32, 2, 16), dim3(256), 0, stream, q_s, s_key, t_key, scores);
  hipLaunchKernelGGL(k_softmax, dim3(2048), dim3(256), 0, stream, scores);
  hipLaunchKernelGGL(k_ctx, dim3(32, 8, 4), dim3(256), 0, stream, scores, sv_T, tv_T, part);
  hipLaunchKernelGGL(k_out, dim3(8, 32, 1), dim3(256), 0, stream, qc, part, woT,
                     biasc + 5 * 512, d_out, query);
}

// Round 9
// 222.565 us; speedup vs baseline: 1.0205x; 1.0205x over previous
//
#include <hip/hip_runtime.h>
#include <cstdint>

// ---------- types & helpers ----------
typedef __attribute__((ext_vector_type(8))) short short8_t;
typedef __attribute__((ext_vector_type(8))) __bf16 bf16x8_t;
typedef __attribute__((ext_vector_type(4))) float f32x4_t;

__device__ __forceinline__ float bf2f(unsigned short u) {
  return __uint_as_float(((unsigned)u) << 16);
}
__device__ __forceinline__ unsigned short f2bf(float f) {  // RNE
  unsigned u = __float_as_uint(f);
  u += 0x7FFFu + ((u >> 16) & 1u);
  return (unsigned short)(u >> 16);
}
__device__ __forceinline__ unsigned short f2bf_rhu(float f) {  // round-half-up (hot loops)
  return (unsigned short)((__float_as_uint(f) + 0x8000u) >> 16);
}

// MFMA wrapper: tolerate either builtin signature (short8 or bf16x8 operands).
template <typename V>
__device__ __forceinline__ auto mfma16_impl(V a, V b, f32x4_t c, int)
    -> decltype(__builtin_amdgcn_mfma_f32_16x16x32_bf16(a, b, c, 0, 0, 0)) {
  return __builtin_amdgcn_mfma_f32_16x16x32_bf16(a, b, c, 0, 0, 0);
}
template <typename V>
__device__ __forceinline__ f32x4_t mfma16_impl(V a, V b, f32x4_t c, long) {
  bf16x8_t ab = __builtin_bit_cast(bf16x8_t, a);
  bf16x8_t bb = __builtin_bit_cast(bf16x8_t, b);
  return __builtin_amdgcn_mfma_f32_16x16x32_bf16(ab, bb, c, 0, 0, 0);
}
__device__ __forceinline__ f32x4_t MFMA16(short8_t a, short8_t b, f32x4_t c) {
  return mfma16_impl(a, b, c, 0);
}

#define KPITCH 72   // 64-col K-tiles padded to 72 (k_out)
#define SPITCH 136  // 128-col tiles (k_scores)

#define FRAG_VARS                                                       \
  const int tid = threadIdx.x;                                          \
  const int lane = tid & 63;                                            \
  const int wv = tid >> 6;                                              \
  const int mw = (wv >> 1) << 5;                                        \
  const int nw = (wv & 1) << 5;                                         \
  const int fr = lane & 15;                                             \
  const int fq = lane >> 4;                                             \
  f32x4_t acc00 = {0.f, 0.f, 0.f, 0.f};                                 \
  f32x4_t acc01 = acc00, acc10 = acc00, acc11 = acc00;

// Body sees: ml (local m), nl (local n), vv (float value). Variadic for commas.
#define GEMM_EPILOGUE(...)                                              \
  {                                                                     \
    const f32x4_t accs_[4] = {acc00, acc01, acc10, acc11};              \
    _Pragma("unroll") for (int im_ = 0; im_ < 2; ++im_)                 \
    _Pragma("unroll") for (int jn_ = 0; jn_ < 2; ++jn_) {               \
      f32x4_t aa_ = accs_[im_ * 2 + jn_];                               \
      const int ml0_ = mw + im_ * 16 + fq * 4;                          \
      const int nl = nw + jn_ * 16 + fr;                                \
      _Pragma("unroll") for (int r_ = 0; r_ < 4; ++r_) {                \
        const int ml = ml0_ + r_;                                       \
        const float vv = aa_[r_];                                       \
        __VA_ARGS__;                                                    \
      }                                                                 \
    }                                                                   \
  }

// MFMA group for one 32-wide k-slice read from KPITCH LDS tiles (k_out).
#define MFMA_K32(aLbuf, bLbuf, kf)                                      \
  do {                                                                  \
    short8_t a0_ = *(const short8_t*)&aLbuf[(mw + fr) * KPITCH + (kf)]; \
    short8_t a1_ = *(const short8_t*)&aLbuf[(mw + 16 + fr) * KPITCH + (kf)]; \
    short8_t b0_ = *(const short8_t*)&bLbuf[(nw + fr) * KPITCH + (kf)]; \
    short8_t b1_ = *(const short8_t*)&bLbuf[(nw + 16 + fr) * KPITCH + (kf)]; \
    acc00 = MFMA16(a0_, b0_, acc00);                                    \
    acc01 = MFMA16(a0_, b1_, acc01);                                    \
    acc10 = MFMA16(a1_, b0_, acc10);                                    \
    acc11 = MFMA16(a1_, b1_, acc11);                                    \
  } while (0)

// bf16x8 (short8) * scalar f32 -> bf16x8
__device__ __forceinline__ short8_t prods8(short8_t t, float s) {
  union { short8_t v; unsigned short u[8]; } in, r;
  in.v = t;
#pragma unroll
  for (int j = 0; j < 8; ++j) r.u[j] = f2bf_rhu(bf2f(in.u[j]) * s);
  return r.v;
}

// ---------- async 16B/lane global->LDS (dest = wave-uniform base + lane*16) ----------
#if __has_builtin(__builtin_amdgcn_global_load_lds)
__device__ __forceinline__ void gload16(const void* g, void* lds_wave_base) {
  __builtin_amdgcn_global_load_lds(g, lds_wave_base, 16, 0, 0);
}
#else
__device__ __forceinline__ void gload16(const void* g, void* lds_wave_base) {
  const int lane = threadIdx.x & 63;  // synchronous fallback, same slot mapping
  ((uint4*)lds_wave_base)[lane] = *(const uint4*)g;
}
#endif

// ---------- inline dtype detector (per-block, deterministic, L2-broadcast) ----------
__device__ __forceinline__ int detect_f32(const void* q, int tid, int* sh) {
  const unsigned short* p = (const unsigned short*)q;
  int w = 0;
  for (int i = tid; i < 512; i += 256) {
    float v = bf2f(p[i]);
    float av = fabsf(v);
    if (!(av <= 1e4f) || (v != 0.f && av < 1e-10f)) ++w;  // NaN fails av<=1e4
  }
#pragma unroll
  for (int off = 32; off > 0; off >>= 1) w += __shfl_xor(w, off);
  if ((tid & 63) == 0) sh[tid >> 6] = w;
  __syncthreads();
  return (sh[0] + sh[1] + sh[2] + sh[3]) > 40;  // 1 = inputs are f32
}

__device__ __forceinline__ unsigned short load_as_bf16(const void* p, size_t i, int f32mode) {
  return f32mode ? f2bf(((const float*)p)[i]) : ((const unsigned short*)p)[i];
}

// ---------- merged prep: convert (z<9) + weight transpose (z>=9), flag inline ----------
struct PrepArgs {
  const void* csrc[9];
  unsigned short* cdst[9];
  int cn[9];
  const void* tsrc[6];
  unsigned short* tdst[6];
  int tK[6];
};

__global__ __launch_bounds__(256) void k_prep(PrepArgs a) {
  __shared__ int shw[4];
  __shared__ unsigned short t[32][33];
  const int f32mode = detect_f32(a.csrc[0], threadIdx.x, shw);
  const int z = blockIdx.z;
  if (z < 9) {
    const int n = a.cn[z];
    const int bid = blockIdx.y * 16 + blockIdx.x;  // 0..767
    const int stride = 768 * 256;
    for (int i = bid * 256 + threadIdx.x; i < n; i += stride)
      a.cdst[z][i] = load_as_bf16(a.csrc[z], i, f32mode);
  } else {
    const int w = z - 9;
    const int K = a.tK[w];
    const int k0 = blockIdx.y * 32, n0 = blockIdx.x * 32;
    if (k0 >= K) return;
    const int tx = threadIdx.x & 31, ty = threadIdx.x >> 5;
    const void* s = a.tsrc[w];
#pragma unroll
    for (int i = 0; i < 4; ++i)
      t[ty + i * 8][tx] = load_as_bf16(s, (size_t)(k0 + ty + i * 8) * 512 + n0 + tx, f32mode);
    __syncthreads();
    unsigned short* d = a.tdst[w];
#pragma unroll
    for (int i = 0; i < 4; ++i)
      d[(size_t)(n0 + ty + i * 8) * K + k0 + tx] = t[tx][ty + i * 8];
  }
}

// ---------- five projections: async global_load_lds, dbuf, XOR-swizzled LDS ----------
// Layout: per buffer, A and B tiles stored unpadded 64x64; 16B chunk at stored
// slot (r, c8s) holds global chunk (r, c8s ^ (r&7)).  Staging: wave w / half h
// writes rows h*32+w*8..+7 as one contiguous 1KB window (lane l -> slot l).
// Fragment read slot: (ks*4+fq) ^ (fr&7) -> 2 lanes per 4-bank group (free).
struct ProjArgs {
  const unsigned short* A[5];
  const unsigned short* W[5];
  const unsigned short* bias[5];
  unsigned short* out[5];
};

__global__ __launch_bounds__(256) void k_proj(ProjArgs args) {
  const int id = blockIdx.x;  // 0..767, all live
  int op, by, bx;
  if (id < 256) {
    op = 0; by = id >> 3; bx = id & 7;
  } else {
    int r2 = id - 256;
    op = 1 + (r2 >> 7); r2 &= 127; by = r2 >> 3; bx = r2 & 7;
  }
  const int m0 = by * 64, n0 = bx * 64;
  const unsigned short* A = args.A[op];
  const unsigned short* W = args.W[op];
  FRAG_VARS;
  __shared__ __align__(16) unsigned short sm[2][2][64 * 64];  // [buf][A=0/B=1] 32KB
  const int srow = lane >> 3;                       // 0..7 within wave's 8 rows
  const int scol = ((lane & 7) ^ srow) * 8;         // swizzled global elem offset
  // prologue: issue buf0 loads
#pragma unroll
  for (int h = 0; h < 2; ++h) {
    const int row = h * 32 + wv * 8;
    gload16(&A[(size_t)(m0 + row + srow) * 1024 + scol], &sm[0][0][row * 64]);
    gload16(&W[(size_t)(n0 + row + srow) * 1024 + scol], &sm[0][1][row * 64]);
  }
  const int cs0 = ((fq) ^ (fr & 7)) * 8;        // ks=0 slot
  const int cs1 = ((4 + fq) ^ (fr & 7)) * 8;    // ks=1 slot
  for (int kc = 0; kc < 16; ++kc) {
    const int cur = kc & 1;
    __syncthreads();  // drains this wave's loads for buf[cur] (vmcnt0) + sync
    if (kc + 1 < 16) {
      const int nxt = cur ^ 1;
      const int k0 = (kc + 1) * 64;
#pragma unroll
      for (int h = 0; h < 2; ++h) {
        const int row = h * 32 + wv * 8;
        gload16(&A[(size_t)(m0 + row + srow) * 1024 + k0 + scol], &sm[nxt][0][row * 64]);
        gload16(&W[(size_t)(n0 + row + srow) * 1024 + k0 + scol], &sm[nxt][1][row * 64]);
      }
    }
    const unsigned short* Ab = sm[cur][0];
    const unsigned short* Bb = sm[cur][1];
    {
      short8_t a0 = *(const short8_t*)&Ab[(mw + fr) * 64 + cs0];
      short8_t a1 = *(const short8_t*)&Ab[(mw + 16 + fr) * 64 + cs0];
      short8_t b0 = *(const short8_t*)&Bb[(nw + fr) * 64 + cs0];
      short8_t b1 = *(const short8_t*)&Bb[(nw + 16 + fr) * 64 + cs0];
      acc00 = MFMA16(a0, b0, acc00);
      acc01 = MFMA16(a0, b1, acc01);
      acc10 = MFMA16(a1, b0, acc10);
      acc11 = MFMA16(a1, b1, acc11);
    }
    {
      short8_t a0 = *(const short8_t*)&Ab[(mw + fr) * 64 + cs1];
      short8_t a1 = *(const short8_t*)&Ab[(mw + 16 + fr) * 64 + cs1];
      short8_t b0 = *(const short8_t*)&Bb[(nw + fr) * 64 + cs1];
      short8_t b1 = *(const short8_t*)&Bb[(nw + 16 + fr) * 64 + cs1];
      acc00 = MFMA16(a0, b0, acc00);
      acc01 = MFMA16(a0, b1, acc01);
      acc10 = MFMA16(a1, b0, acc10);
      acc11 = MFMA16(a1, b1, acc11);
    }
  }
  const float scale = (op == 0) ? 0.044194173824159216f : 1.0f;
  const unsigned short* bias = args.bias[op];
  unsigned short* out = args.out[op];
  GEMM_EPILOGUE({
    const float v = (vv + bf2f(bias[n0 + nl])) * scale;
    const int m = m0 + ml;
    const int n = n0 + nl;
    if (op < 3) {
      out[(size_t)m * 512 + n] = f2bf(v);
    } else {
      const int bb = m >> 6;
      const int ss = m & 63;
      out[(size_t)bb * 32768 + (size_t)n * 64 + ss] = f2bf(v);
    }
  });
}

// ---------- scores: reuse-heavy LDS-staged (R5 known-good) ----------
__global__ __launch_bounds__(256) void k_scores(
    const unsigned short* __restrict__ qs, const unsigned short* __restrict__ skey,
    const unsigned short* __restrict__ tkey, unsigned short* __restrict__ scores) {
  const int b = blockIdx.z;
  const int m0 = blockIdx.y * 64;
  const int sx = blockIdx.x;  // s = sx*2 + {0,1}
  const int tid = threadIdx.x;
  const int lane = tid & 63;
  const int wv = tid >> 6;
  const int mw = (wv >> 1) << 5;
  const int nw = (wv & 1) << 5;
  const int fr = lane & 15;
  const int fq = lane >> 4;
  __shared__ __align__(16) unsigned short qL[64 * SPITCH];
  __shared__ __align__(16) unsigned short tkL[64 * SPITCH];
  __shared__ __align__(16) unsigned short skL[2 * SPITCH];
  f32x4_t acc[2][4];
#pragma unroll
  for (int s = 0; s < 2; ++s)
#pragma unroll
    for (int i = 0; i < 4; ++i) acc[s][i] = (f32x4_t){0.f, 0.f, 0.f, 0.f};
  const unsigned short* qb = qs + ((size_t)b * 128 + m0) * 512;
  const unsigned short* tkb = tkey + (size_t)b * 64 * 512;
  const unsigned short* skb = skey + ((size_t)b * 64 + sx * 2) * 512;
  for (int kc = 0; kc < 4; ++kc) {
    const int kbase = kc * 128;
    __syncthreads();
#pragma unroll
    for (int i = 0; i < 4; ++i) {
      const int u = tid + i * 256;
      const int r = u >> 4, c = (u & 15) * 8;
      *(uint4*)&qL[r * SPITCH + c] = *(const uint4*)&qb[(size_t)r * 512 + kbase + c];
      *(uint4*)&tkL[r * SPITCH + c] = *(const uint4*)&tkb[(size_t)r * 512 + kbase + c];
    }
    if (tid < 32) {
      const int r = tid >> 4, c = (tid & 15) * 8;
      *(uint4*)&skL[r * SPITCH + c] = *(const uint4*)&skb[(size_t)r * 512 + kbase + c];
    }
    __syncthreads();
#pragma unroll
    for (int ks = 0; ks < 4; ++ks) {
      const int kf = ks * 32 + fq * 8;
      short8_t a0 = *(const short8_t*)&qL[(mw + fr) * SPITCH + kf];
      short8_t a1 = *(const short8_t*)&qL[(mw + 16 + fr) * SPITCH + kf];
      uint4 tq[2];
      tq[0] = *(const uint4*)&tkL[(nw + fr) * SPITCH + kf];
      tq[1] = *(const uint4*)&tkL[(nw + 16 + fr) * SPITCH + kf];
      float tlo[2][4], thi[2][4];
#pragma unroll
      for (int h = 0; h < 2; ++h) {
        const unsigned* tw = (const unsigned*)&tq[h];
#pragma unroll
        for (int j = 0; j < 4; ++j) {
          tlo[h][j] = __uint_as_float(tw[j] << 16);
          thi[h][j] = __uint_as_float(tw[j] & 0xffff0000u);
        }
      }
#pragma unroll
      for (int s = 0; s < 2; ++s) {
        uint4 skq = *(const uint4*)&skL[s * SPITCH + kf];
        const unsigned* sw = (const unsigned*)&skq;
        union { short8_t v; unsigned w[4]; } b0, b1;
#pragma unroll
        for (int j = 0; j < 4; ++j) {
          const float slo = __uint_as_float(sw[j] << 16);
          const float shi = __uint_as_float(sw[j] & 0xffff0000u);
          b0.w[j] = __builtin_amdgcn_perm(__float_as_uint(thi[0][j] * shi),
                                          __float_as_uint(tlo[0][j] * slo), 0x07060302);
          b1.w[j] = __builtin_amdgcn_perm(__float_as_uint(thi[1][j] * shi),
                                          __float_as_uint(tlo[1][j] * slo), 0x07060302);
        }
        acc[s][0] = MFMA16(a0, b0.v, acc[s][0]);
        acc[s][1] = MFMA16(a0, b1.v, acc[s][1]);
        acc[s][2] = MFMA16(a1, b0.v, acc[s][2]);
        acc[s][3] = MFMA16(a1, b1.v, acc[s][3]);
      }
    }
  }
#pragma unroll
  for (int s = 0; s < 2; ++s) {
    unsigned short* out = scores + ((size_t)b * 128 + m0) * 4096 + (size_t)(sx * 2 + s) * 64;
#pragma unroll
    for (int im = 0; im < 2; ++im)
#pragma unroll
      for (int jn = 0; jn < 2; ++jn) {
        f32x4_t aa = acc[s][im * 2 + jn];
        const int col = nw + jn * 16 + fr;
#pragma unroll
        for (int r = 0; r < 4; ++r) {
          const int row = mw + im * 16 + fq * 4 + r;
          out[(size_t)row * 4096 + col] = f2bf(aa[r]);
        }
      }
  }
}

// ---------- in-place softmax over each row of 4096 ----------
__global__ __launch_bounds__(256) void k_softmax(unsigned short* __restrict__ s) {
  unsigned short* p = s + (size_t)blockIdx.x * 4096;
  const int t = threadIdx.x;
  union U8 { uint4 q; unsigned short u[8]; };
  U8 a, b;
  a.q = *(const uint4*)&p[t * 16];
  b.q = *(const uint4*)&p[t * 16 + 8];
  float x[16];
#pragma unroll
  for (int j = 0; j < 8; ++j) { x[j] = bf2f(a.u[j]); x[8 + j] = bf2f(b.u[j]); }
  float m = x[0];
#pragma unroll
  for (int j = 1; j < 16; ++j) m = fmaxf(m, x[j]);
  for (int off = 32; off > 0; off >>= 1) m = fmaxf(m, __shfl_xor(m, off));
  __shared__ float redm[4], reds[4];
  if ((t & 63) == 0) redm[t >> 6] = m;
  __syncthreads();
  m = fmaxf(fmaxf(redm[0], redm[1]), fmaxf(redm[2], redm[3]));
  float sum = 0.f;
#pragma unroll
  for (int j = 0; j < 16; ++j) { x[j] = __expf(x[j] - m); sum += x[j]; }
  for (int off = 32; off > 0; off >>= 1) sum += __shfl_xor(sum, off);
  if ((t & 63) == 0) reds[t >> 6] = sum;
  __syncthreads();
  sum = reds[0] + reds[1] + reds[2] + reds[3];
  const float inv = 1.0f / sum;
#pragma unroll
  for (int j = 0; j < 8; ++j) {
    a.u[j] = f2bf(x[j] * inv);
    b.u[j] = f2bf(x[8 + j] * inv);
  }
  *(uint4*)&p[t * 16] = a.q;
  *(uint4*)&p[t * 16 + 8] = b.q;
}

// ---------- ctx partials: split-K x4 over s; bf16 partials (R5 known-good) ----------
__global__ __launch_bounds__(256) void k_ctx(
    const unsigned short* __restrict__ p, const unsigned short* __restrict__ svT,
    const unsigned short* __restrict__ tvT, unsigned short* __restrict__ part) {
  const int b = blockIdx.x >> 1;
  const int m0 = (blockIdx.x & 1) * 64;
  const int n0 = blockIdx.y * 64;
  const int z = blockIdx.z;
  FRAG_VARS;
  __shared__ __align__(16) unsigned short tvl[64 * 72];
  __shared__ __align__(16) unsigned short svl[64 * 24];
  {
    const unsigned short* tvb = tvT + (size_t)b * 32768 + (size_t)n0 * 64;
    const unsigned short* svb = svT + (size_t)b * 32768 + (size_t)n0 * 64 + z * 16;
#pragma unroll
    for (int it = 0; it < 2; ++it) {
      const int idx = tid + it * 256;
      const int r = idx >> 3, c = (idx & 7) * 8;
      *(uint4*)&tvl[r * 72 + c] = *(const uint4*)&tvb[(size_t)r * 64 + c];
    }
    if (tid < 128) {
      const int r = tid >> 1, c = (tid & 1) * 8;
      *(uint4*)&svl[r * 24 + c] = *(const uint4*)&svb[(size_t)r * 64 + c];
    }
  }
  __syncthreads();
  const unsigned short* ar0 =
      p + ((size_t)b * 128 + m0 + mw + fr) * 4096 + z * 1024 + fq * 8;
  const unsigned short* ar1 = ar0 + (size_t)16 * 4096;
  uint4 pa0[4], pa1[4];
#pragma unroll
  for (int i = 0; i < 4; ++i) {
    pa0[i] = *(const uint4*)(ar0 + i * 32);
    pa1[i] = *(const uint4*)(ar1 + i * 32);
  }
#pragma unroll 4
  for (int ks = 0; ks < 32; ++ks) {
    const int sl = ks & 3;
    short8_t av0 = __builtin_bit_cast(short8_t, pa0[sl]);
    short8_t av1 = __builtin_bit_cast(short8_t, pa1[sl]);
    const int kn = ks + 4;
    if (kn < 32) {
      pa0[sl] = *(const uint4*)(ar0 + kn * 32);
      pa1[sl] = *(const uint4*)(ar1 + kn * 32);
    }
    const int s_l = ks >> 1;
    const int t0 = (ks & 1) * 32;
    short8_t tv0 = *(const short8_t*)&tvl[(nw + fr) * 72 + t0 + fq * 8];
    short8_t tv1 = *(const short8_t*)&tvl[(nw + 16 + fr) * 72 + t0 + fq * 8];
    const float sv0 = bf2f(svl[(nw + fr) * 24 + s_l]);
    const float sv1 = bf2f(svl[(nw + 16 + fr) * 24 + s_l]);
    short8_t bv0 = prods8(tv0, sv0);
    short8_t bv1 = prods8(tv1, sv1);
    acc00 = MFMA16(av0, bv0, acc00);
    acc01 = MFMA16(av0, bv1, acc01);
    acc10 = MFMA16(av1, bv0, acc10);
    acc11 = MFMA16(av1, bv1, acc11);
  }
  unsigned short* out = part + ((size_t)z * 2048 + (size_t)b * 128 + m0) * 512 + n0;
  GEMM_EPILOGUE({ out[(size_t)ml * 512 + nl] = f2bf(vv); });
}

// ---------- out = relu(concat(query, sum_z part) @ Wo + bo); K=64, reduce fused ----------
__global__ __launch_bounds__(256) void k_out(
    const unsigned short* __restrict__ query, const unsigned short* __restrict__ part,
    const unsigned short* __restrict__ WoT, const unsigned short* __restrict__ bo,
    void* __restrict__ outv, const void* __restrict__ rawq) {
  __shared__ int shw[4];
  const int f32mode = detect_f32(rawq, threadIdx.x, shw);
  const int m0 = blockIdx.y * 64, n0 = blockIdx.x * 64;
  FRAG_VARS;
  __shared__ __align__(16) unsigned short aL[64 * KPITCH];
  __shared__ __align__(16) unsigned short bL[64 * KPITCH];
  const int r = tid >> 3, c = (tid & 7) * 8;
  const size_t N = (size_t)2048 * 512;
  for (int k0 = 0; k0 < 1536; k0 += 64) {
    uint4 a0v, a1v;
    if (k0 < 1024) {
      a0v = *(const uint4*)&query[(size_t)(m0 + r) * 1024 + k0 + c];
      a1v = *(const uint4*)&query[(size_t)(m0 + r + 32) * 1024 + k0 + c];
    } else {
      const int kk = k0 - 1024;
      float s0[8], s1[8];
#pragma unroll
      for (int j = 0; j < 8; ++j) { s0[j] = 0.f; s1[j] = 0.f; }
#pragma unroll
      for (int z = 0; z < 4; ++z) {
        union { uint4 q; unsigned short u[8]; } t0, t1;
        t0.q = *(const uint4*)&part[z * N + (size_t)(m0 + r) * 512 + kk + c];
        t1.q = *(const uint4*)&part[z * N + (size_t)(m0 + r + 32) * 512 + kk + c];
#pragma unroll
        for (int j = 0; j < 8; ++j) { s0[j] += bf2f(t0.u[j]); s1[j] += bf2f(t1.u[j]); }
      }
      union { uint4 q; unsigned short u[8]; } o0, o1;
#pragma unroll
      for (int j = 0; j < 8; ++j) { o0.u[j] = f2bf(s0[j]); o1.u[j] = f2bf(s1[j]); }
      a0v = o0.q; a1v = o1.q;
    }
    uint4 b0v = *(const uint4*)&WoT[(size_t)(n0 + r) * 1536 + k0 + c];
    uint4 b1v = *(const uint4*)&WoT[(size_t)(n0 + r + 32) * 1536 + k0 + c];
    __syncthreads();
    *(uint4*)&aL[r * KPITCH + c] = a0v;
    *(uint4*)&aL[(r + 32) * KPITCH + c] = a1v;
    *(uint4*)&bL[r * KPITCH + c] = b0v;
    *(uint4*)&bL[(r + 32) * KPITCH + c] = b1v;
    __syncthreads();
    MFMA_K32(aL, bL, fq * 8);
    MFMA_K32(aL, bL, 32 + fq * 8);
  }
  GEMM_EPILOGUE({
    float v = fmaxf(vv + bf2f(bo[n0 + nl]), 0.f);
    const size_t idx = (size_t)(m0 + ml) * 512 + n0 + nl;
    if (f32mode)
      ((float*)outv)[idx] = v;
    else
      ((unsigned short*)outv)[idx] = f2bf(v);
  });
}

// ---------- launch ----------
extern "C" void kernel_launch(void* const* d_in, const int* in_sizes, int n_in,
                              void* d_out, int out_size, void* d_ws, size_t ws_size,
                              hipStream_t stream) {
  const void* query = d_in[0];
  const void* src = d_in[1];
  const void* trg = d_in[2];
  const void* Wq = d_in[3];
  const void* bq = d_in[4];
  const void* Ws = d_in[5];
  const void* bs = d_in[6];
  const void* Wt = d_in[7];
  const void* bt = d_in[8];
  const void* Wsv = d_in[9];
  const void* bsv = d_in[10];
  const void* Wtv = d_in[11];
  const void* btv = d_in[12];
  const void* Wo = d_in[13];
  const void* bo = d_in[14];

  char* ws = (char*)d_ws;
  size_t off = 0;
  auto alloc = [&](size_t bytes) {
    char* ptr = ws + off;
    off = (off + bytes + 255) & ~(size_t)255;
    return ptr;
  };
  unsigned short* qc = (unsigned short*)alloc((size_t)2048 * 1024 * 2);
  unsigned short* srcc = (unsigned short*)alloc((size_t)1024 * 1024 * 2);
  unsigned short* trgc = (unsigned short*)alloc((size_t)1024 * 1024 * 2);
  unsigned short* biasc = (unsigned short*)alloc((size_t)6 * 512 * 2);
  unsigned short* wT = (unsigned short*)alloc((size_t)5 * 524288 * 2);
  unsigned short* woT = (unsigned short*)alloc((size_t)512 * 1536 * 2);
  unsigned short* q_s = (unsigned short*)alloc((size_t)2048 * 512 * 2);
  unsigned short* s_key = (unsigned short*)alloc((size_t)1024 * 512 * 2);
  unsigned short* t_key = (unsigned short*)alloc((size_t)1024 * 512 * 2);
  unsigned short* sv_T = (unsigned short*)alloc((size_t)16 * 512 * 64 * 2);
  unsigned short* tv_T = (unsigned short*)alloc((size_t)16 * 512 * 64 * 2);
  unsigned short* scores = (unsigned short*)alloc((size_t)2048 * 4096 * 2);
  unsigned short* part = (unsigned short*)alloc((size_t)4 * 2048 * 512 * 2);
  (void)ws_size; (void)in_sizes; (void)n_in; (void)out_size;

  PrepArgs pr;
  pr.csrc[0] = query; pr.csrc[1] = src; pr.csrc[2] = trg;
  pr.csrc[3] = bq; pr.csrc[4] = bs; pr.csrc[5] = bt;
  pr.csrc[6] = bsv; pr.csrc[7] = btv; pr.csrc[8] = bo;
  pr.cdst[0] = qc; pr.cdst[1] = srcc; pr.cdst[2] = trgc;
  for (int i = 0; i < 6; ++i) pr.cdst[3 + i] = biasc + i * 512;
  pr.cn[0] = 2048 * 1024; pr.cn[1] = 1024 * 1024; pr.cn[2] = 1024 * 1024;
  for (int i = 0; i < 6; ++i) pr.cn[3 + i] = 512;
  pr.tsrc[0] = Wq; pr.tsrc[1] = Ws; pr.tsrc[2] = Wt;
  pr.tsrc[3] = Wsv; pr.tsrc[4] = Wtv; pr.tsrc[5] = Wo;
  for (int i = 0; i < 5; ++i) { pr.tdst[i] = wT + (size_t)i * 524288; pr.tK[i] = 1024; }
  pr.tdst[5] = woT; pr.tK[5] = 1536;
  hipLaunchKernelGGL(k_prep, dim3(16, 48, 15), dim3(256), 0, stream, pr);

  ProjArgs pa;
  pa.A[0] = qc; pa.A[1] = srcc; pa.A[2] = trgc; pa.A[3] = srcc; pa.A[4] = trgc;
  for (int i = 0; i < 5; ++i) pa.W[i] = wT + (size_t)i * 524288;
  for (int i = 0; i < 5; ++i) pa.bias[i] = biasc + i * 512;
  pa.out[0] = q_s; pa.out[1] = s_key; pa.out[2] = t_key; pa.out[3] = sv_T; pa.out[4] = tv_T;
  hipLaunchKernelGGL(k_proj, dim3(768), dim3(256), 0, stream, pa);

  hipLaunchKernelGGL(k_scores, dim3(32, 2, 16), dim3(256), 0, stream, q_s, s_key, t_key, scores);
  hipLaunchKernelGGL(k_softmax, dim3(2048), dim3(256), 0, stream, scores);
  hipLaunchKernelGGL(k_ctx, dim3(32, 8, 4), dim3(256), 0, stream, scores, sv_T, tv_T, part);
  hipLaunchKernelGGL(k_out, dim3(8, 32, 1), dim3(256), 0, stream, qc, part, woT,
                     biasc + 5 * 512, d_out, query);
}

// Round 10
// 210.400 us; speedup vs baseline: 1.0794x; 1.0578x over previous
//
#include <hip/hip_runtime.h>
#include <cstdint>

// ---------- types & helpers ----------
typedef __attribute__((ext_vector_type(8))) short short8_t;
typedef __attribute__((ext_vector_type(8))) __bf16 bf16x8_t;
typedef __attribute__((ext_vector_type(4))) float f32x4_t;

__device__ __forceinline__ float bf2f(unsigned short u) {
  return __uint_as_float(((unsigned)u) << 16);
}
__device__ __forceinline__ unsigned short f2bf(float f) {  // RNE
  unsigned u = __float_as_uint(f);
  u += 0x7FFFu + ((u >> 16) & 1u);
  return (unsigned short)(u >> 16);
}
__device__ __forceinline__ unsigned short f2bf_rhu(float f) {  // round-half-up (hot loops)
  return (unsigned short)((__float_as_uint(f) + 0x8000u) >> 16);
}

// MFMA wrapper: tolerate either builtin signature (short8 or bf16x8 operands).
template <typename V>
__device__ __forceinline__ auto mfma16_impl(V a, V b, f32x4_t c, int)
    -> decltype(__builtin_amdgcn_mfma_f32_16x16x32_bf16(a, b, c, 0, 0, 0)) {
  return __builtin_amdgcn_mfma_f32_16x16x32_bf16(a, b, c, 0, 0, 0);
}
template <typename V>
__device__ __forceinline__ f32x4_t mfma16_impl(V a, V b, f32x4_t c, long) {
  bf16x8_t ab = __builtin_bit_cast(bf16x8_t, a);
  bf16x8_t bb = __builtin_bit_cast(bf16x8_t, b);
  return __builtin_amdgcn_mfma_f32_16x16x32_bf16(ab, bb, c, 0, 0, 0);
}
__device__ __forceinline__ f32x4_t MFMA16(short8_t a, short8_t b, f32x4_t c) {
  return mfma16_impl(a, b, c, 0);
}

#define KPITCH 72   // 64-col K-tiles padded to 72 (k_out)

#define FRAG_VARS                                                       \
  const int tid = threadIdx.x;                                          \
  const int lane = tid & 63;                                            \
  const int wv = tid >> 6;                                              \
  const int mw = (wv >> 1) << 5;                                        \
  const int nw = (wv & 1) << 5;                                         \
  const int fr = lane & 15;                                             \
  const int fq = lane >> 4;                                             \
  f32x4_t acc00 = {0.f, 0.f, 0.f, 0.f};                                 \
  f32x4_t acc01 = acc00, acc10 = acc00, acc11 = acc00;

// Body sees: ml (local m), nl (local n), vv (float value). Variadic for commas.
#define GEMM_EPILOGUE(...)                                              \
  {                                                                     \
    const f32x4_t accs_[4] = {acc00, acc01, acc10, acc11};              \
    _Pragma("unroll") for (int im_ = 0; im_ < 2; ++im_)                 \
    _Pragma("unroll") for (int jn_ = 0; jn_ < 2; ++jn_) {               \
      f32x4_t aa_ = accs_[im_ * 2 + jn_];                               \
      const int ml0_ = mw + im_ * 16 + fq * 4;                          \
      const int nl = nw + jn_ * 16 + fr;                                \
      _Pragma("unroll") for (int r_ = 0; r_ < 4; ++r_) {                \
        const int ml = ml0_ + r_;                                       \
        const float vv = aa_[r_];                                       \
        __VA_ARGS__;                                                    \
      }                                                                 \
    }                                                                   \
  }

// MFMA group for one 32-wide k-slice read from KPITCH LDS tiles (k_out).
#define MFMA_K32(aLbuf, bLbuf, kf)                                      \
  do {                                                                  \
    short8_t a0_ = *(const short8_t*)&aLbuf[(mw + fr) * KPITCH + (kf)]; \
    short8_t a1_ = *(const short8_t*)&aLbuf[(mw + 16 + fr) * KPITCH + (kf)]; \
    short8_t b0_ = *(const short8_t*)&bLbuf[(nw + fr) * KPITCH + (kf)]; \
    short8_t b1_ = *(const short8_t*)&bLbuf[(nw + 16 + fr) * KPITCH + (kf)]; \
    acc00 = MFMA16(a0_, b0_, acc00);                                    \
    acc01 = MFMA16(a0_, b1_, acc01);                                    \
    acc10 = MFMA16(a1_, b0_, acc10);                                    \
    acc11 = MFMA16(a1_, b1_, acc11);                                    \
  } while (0)

// bf16x8 (short8) * scalar f32 -> bf16x8
__device__ __forceinline__ short8_t prods8(short8_t t, float s) {
  union { short8_t v; unsigned short u[8]; } in, r;
  in.v = t;
#pragma unroll
  for (int j = 0; j < 8; ++j) r.u[j] = f2bf_rhu(bf2f(in.u[j]) * s);
  return r.v;
}

// ---------- async 16B/lane global->LDS (dest = wave-uniform base + lane*16) ----------
#if __has_builtin(__builtin_amdgcn_global_load_lds)
__device__ __forceinline__ void gload16(const void* g, void* lds_wave_base) {
  __builtin_amdgcn_global_load_lds(g, lds_wave_base, 16, 0, 0);
}
#else
__device__ __forceinline__ void gload16(const void* g, void* lds_wave_base) {
  const int lane = threadIdx.x & 63;  // synchronous fallback, same slot mapping
  ((uint4*)lds_wave_base)[lane] = *(const uint4*)g;
}
#endif

// ---------- inline dtype detector (per-block, deterministic, L2-broadcast) ----------
__device__ __forceinline__ int detect_f32(const void* q, int tid, int* sh) {
  const unsigned short* p = (const unsigned short*)q;
  int w = 0;
  for (int i = tid; i < 512; i += 256) {
    float v = bf2f(p[i]);
    float av = fabsf(v);
    if (!(av <= 1e4f) || (v != 0.f && av < 1e-10f)) ++w;  // NaN fails av<=1e4
  }
#pragma unroll
  for (int off = 32; off > 0; off >>= 1) w += __shfl_xor(w, off);
  if ((tid & 63) == 0) sh[tid >> 6] = w;
  __syncthreads();
  return (sh[0] + sh[1] + sh[2] + sh[3]) > 40;  // 1 = inputs are f32
}

__device__ __forceinline__ unsigned short load_as_bf16(const void* p, size_t i, int f32mode) {
  return f32mode ? f2bf(((const float*)p)[i]) : ((const unsigned short*)p)[i];
}

// ---------- merged prep: convert (z<9) + weight transpose (z>=9), flag inline ----------
struct PrepArgs {
  const void* csrc[9];
  unsigned short* cdst[9];
  int cn[9];
  const void* tsrc[6];
  unsigned short* tdst[6];
  int tK[6];
};

__global__ __launch_bounds__(256) void k_prep(PrepArgs a) {
  __shared__ int shw[4];
  __shared__ unsigned short t[32][33];
  const int f32mode = detect_f32(a.csrc[0], threadIdx.x, shw);
  const int z = blockIdx.z;
  if (z < 9) {
    const int n = a.cn[z];
    const int bid = blockIdx.y * 16 + blockIdx.x;  // 0..767
    const int stride = 768 * 256;
    for (int i = bid * 256 + threadIdx.x; i < n; i += stride)
      a.cdst[z][i] = load_as_bf16(a.csrc[z], i, f32mode);
  } else {
    const int w = z - 9;
    const int K = a.tK[w];
    const int k0 = blockIdx.y * 32, n0 = blockIdx.x * 32;
    if (k0 >= K) return;
    const int tx = threadIdx.x & 31, ty = threadIdx.x >> 5;
    const void* s = a.tsrc[w];
#pragma unroll
    for (int i = 0; i < 4; ++i)
      t[ty + i * 8][tx] = load_as_bf16(s, (size_t)(k0 + ty + i * 8) * 512 + n0 + tx, f32mode);
    __syncthreads();
    unsigned short* d = a.tdst[w];
#pragma unroll
    for (int i = 0; i < 4; ++i)
      d[(size_t)(n0 + ty + i * 8) * K + k0 + tx] = t[tx][ty + i * 8];
  }
}

// ---------- five projections: async global_load_lds, dbuf, XOR-swizzled LDS (R9 good) ----------
struct ProjArgs {
  const unsigned short* A[5];
  const unsigned short* W[5];
  const unsigned short* bias[5];
  unsigned short* out[5];
};

__global__ __launch_bounds__(256) void k_proj(ProjArgs args) {
  const int id = blockIdx.x;  // 0..767, all live
  int op, by, bx;
  if (id < 256) {
    op = 0; by = id >> 3; bx = id & 7;
  } else {
    int r2 = id - 256;
    op = 1 + (r2 >> 7); r2 &= 127; by = r2 >> 3; bx = r2 & 7;
  }
  const int m0 = by * 64, n0 = bx * 64;
  const unsigned short* A = args.A[op];
  const unsigned short* W = args.W[op];
  FRAG_VARS;
  __shared__ __align__(16) unsigned short sm[2][2][64 * 64];  // [buf][A=0/B=1] 32KB
  const int srow = lane >> 3;                       // 0..7 within wave's 8 rows
  const int scol = ((lane & 7) ^ srow) * 8;         // swizzled global elem offset
#pragma unroll
  for (int h = 0; h < 2; ++h) {
    const int row = h * 32 + wv * 8;
    gload16(&A[(size_t)(m0 + row + srow) * 1024 + scol], &sm[0][0][row * 64]);
    gload16(&W[(size_t)(n0 + row + srow) * 1024 + scol], &sm[0][1][row * 64]);
  }
  const int cs0 = ((fq) ^ (fr & 7)) * 8;        // ks=0 slot
  const int cs1 = ((4 + fq) ^ (fr & 7)) * 8;    // ks=1 slot
  for (int kc = 0; kc < 16; ++kc) {
    const int cur = kc & 1;
    __syncthreads();
    if (kc + 1 < 16) {
      const int nxt = cur ^ 1;
      const int k0 = (kc + 1) * 64;
#pragma unroll
      for (int h = 0; h < 2; ++h) {
        const int row = h * 32 + wv * 8;
        gload16(&A[(size_t)(m0 + row + srow) * 1024 + k0 + scol], &sm[nxt][0][row * 64]);
        gload16(&W[(size_t)(n0 + row + srow) * 1024 + k0 + scol], &sm[nxt][1][row * 64]);
      }
    }
    const unsigned short* Ab = sm[cur][0];
    const unsigned short* Bb = sm[cur][1];
    {
      short8_t a0 = *(const short8_t*)&Ab[(mw + fr) * 64 + cs0];
      short8_t a1 = *(const short8_t*)&Ab[(mw + 16 + fr) * 64 + cs0];
      short8_t b0 = *(const short8_t*)&Bb[(nw + fr) * 64 + cs0];
      short8_t b1 = *(const short8_t*)&Bb[(nw + 16 + fr) * 64 + cs0];
      acc00 = MFMA16(a0, b0, acc00);
      acc01 = MFMA16(a0, b1, acc01);
      acc10 = MFMA16(a1, b0, acc10);
      acc11 = MFMA16(a1, b1, acc11);
    }
    {
      short8_t a0 = *(const short8_t*)&Ab[(mw + fr) * 64 + cs1];
      short8_t a1 = *(const short8_t*)&Ab[(mw + 16 + fr) * 64 + cs1];
      short8_t b0 = *(const short8_t*)&Bb[(nw + fr) * 64 + cs1];
      short8_t b1 = *(const short8_t*)&Bb[(nw + 16 + fr) * 64 + cs1];
      acc00 = MFMA16(a0, b0, acc00);
      acc01 = MFMA16(a0, b1, acc01);
      acc10 = MFMA16(a1, b0, acc10);
      acc11 = MFMA16(a1, b1, acc11);
    }
  }
  const float scale = (op == 0) ? 0.044194173824159216f : 1.0f;
  const unsigned short* bias = args.bias[op];
  unsigned short* out = args.out[op];
  GEMM_EPILOGUE({
    const float v = (vv + bf2f(bias[n0 + nl])) * scale;
    const int m = m0 + ml;
    const int n = n0 + nl;
    if (op < 3) {
      out[(size_t)m * 512 + n] = f2bf(v);
    } else {
      const int bb = m >> 6;
      const int ss = m & 63;
      out[(size_t)bb * 32768 + (size_t)n * 64 + ss] = f2bf(v);
    }
  });
}

// ---------- scores: async dbuf staging, 64-k chunks, one barrier per chunk ----------
// Block = 64 m x 128 st (2 s x 64 t). sk loaded once; q/tk tiles streamed via
// global_load_lds into XOR-swizzled 64x64 buffers (k_proj-verified mapping).
__global__ __launch_bounds__(256) void k_scores(
    const unsigned short* __restrict__ qs, const unsigned short* __restrict__ skey,
    const unsigned short* __restrict__ tkey, unsigned short* __restrict__ scores) {
  const int b = blockIdx.z;
  const int m0 = blockIdx.y * 64;
  const int sx = blockIdx.x;  // s = sx*2 + {0,1}
  const int tid = threadIdx.x;
  const int lane = tid & 63;
  const int wv = tid >> 6;
  const int mw = (wv >> 1) << 5;
  const int nw = (wv & 1) << 5;
  const int fr = lane & 15;
  const int fq = lane >> 4;
  __shared__ __align__(16) unsigned short qS[2][64 * 64];   // 16KB
  __shared__ __align__(16) unsigned short tkS[2][64 * 64];  // 16KB
  __shared__ __align__(16) unsigned short skL[1024];        // 2KB: 2 s-rows x 512
  f32x4_t acc[2][4];
#pragma unroll
  for (int s = 0; s < 2; ++s)
#pragma unroll
    for (int i = 0; i < 4; ++i) acc[s][i] = (f32x4_t){0.f, 0.f, 0.f, 0.f};
  const unsigned short* qb = qs + ((size_t)b * 128 + m0) * 512;
  const unsigned short* tkb = tkey + (size_t)b * 64 * 512;
  const unsigned short* skb = skey + ((size_t)b * 64 + sx * 2) * 512;
  if (tid < 128) *(uint4*)&skL[tid * 8] = *(const uint4*)&skb[tid * 8];
  const int srow = lane >> 3;
  const int scol = ((lane & 7) ^ srow) * 8;
#pragma unroll
  for (int h = 0; h < 2; ++h) {
    const int row = h * 32 + wv * 8;
    gload16(&qb[(size_t)(row + srow) * 512 + scol], &qS[0][row * 64]);
    gload16(&tkb[(size_t)(row + srow) * 512 + scol], &tkS[0][row * 64]);
  }
  const int cs0 = ((fq) ^ (fr & 7)) * 8;
  const int cs1 = ((4 + fq) ^ (fr & 7)) * 8;
  for (int kc = 0; kc < 8; ++kc) {
    const int cur = kc & 1;
    __syncthreads();  // drains prev prefetch (overlapped with prev compute)
    if (kc + 1 < 8) {
      const int k0 = (kc + 1) * 64;
      const int nxt = cur ^ 1;
#pragma unroll
      for (int h = 0; h < 2; ++h) {
        const int row = h * 32 + wv * 8;
        gload16(&qb[(size_t)(row + srow) * 512 + k0 + scol], &qS[nxt][row * 64]);
        gload16(&tkb[(size_t)(row + srow) * 512 + k0 + scol], &tkS[nxt][row * 64]);
      }
    }
#pragma unroll
    for (int ks = 0; ks < 2; ++ks) {
      const int cs = ks ? cs1 : cs0;
      short8_t a0 = *(const short8_t*)&qS[cur][(mw + fr) * 64 + cs];
      short8_t a1 = *(const short8_t*)&qS[cur][(mw + 16 + fr) * 64 + cs];
      uint4 tq[2];
      tq[0] = *(const uint4*)&tkS[cur][(nw + fr) * 64 + cs];
      tq[1] = *(const uint4*)&tkS[cur][(nw + 16 + fr) * 64 + cs];
      float tlo[2][4], thi[2][4];
#pragma unroll
      for (int h = 0; h < 2; ++h) {
        const unsigned* tw = (const unsigned*)&tq[h];
#pragma unroll
        for (int j = 0; j < 4; ++j) {
          tlo[h][j] = __uint_as_float(tw[j] << 16);
          thi[h][j] = __uint_as_float(tw[j] & 0xffff0000u);
        }
      }
      const int koff = kc * 64 + ks * 32 + fq * 8;  // logical k for sk (broadcast)
#pragma unroll
      for (int s = 0; s < 2; ++s) {
        uint4 skq = *(const uint4*)&skL[s * 512 + koff];
        const unsigned* sw = (const unsigned*)&skq;
        union { short8_t v; unsigned w[4]; } b0, b1;
#pragma unroll
        for (int j = 0; j < 4; ++j) {
          const float slo = __uint_as_float(sw[j] << 16);
          const float shi = __uint_as_float(sw[j] & 0xffff0000u);
          b0.w[j] = __builtin_amdgcn_perm(__float_as_uint(thi[0][j] * shi),
                                          __float_as_uint(tlo[0][j] * slo), 0x07060302);
          b1.w[j] = __builtin_amdgcn_perm(__float_as_uint(thi[1][j] * shi),
                                          __float_as_uint(tlo[1][j] * slo), 0x07060302);
        }
        acc[s][0] = MFMA16(a0, b0.v, acc[s][0]);
        acc[s][1] = MFMA16(a0, b1.v, acc[s][1]);
        acc[s][2] = MFMA16(a1, b0.v, acc[s][2]);
        acc[s][3] = MFMA16(a1, b1.v, acc[s][3]);
      }
    }
  }
#pragma unroll
  for (int s = 0; s < 2; ++s) {
    unsigned short* out = scores + ((size_t)b * 128 + m0) * 4096 + (size_t)(sx * 2 + s) * 64;
#pragma unroll
    for (int im = 0; im < 2; ++im)
#pragma unroll
      for (int jn = 0; jn < 2; ++jn) {
        f32x4_t aa = acc[s][im * 2 + jn];
        const int col = nw + jn * 16 + fr;
#pragma unroll
        for (int r = 0; r < 4; ++r) {
          const int row = mw + im * 16 + fq * 4 + r;
          out[(size_t)row * 4096 + col] = f2bf(aa[r]);
        }
      }
  }
}

// ---------- in-place softmax over each row of 4096 ----------
__global__ __launch_bounds__(256) void k_softmax(unsigned short* __restrict__ s) {
  unsigned short* p = s + (size_t)blockIdx.x * 4096;
  const int t = threadIdx.x;
  union U8 { uint4 q; unsigned short u[8]; };
  U8 a, b;
  a.q = *(const uint4*)&p[t * 16];
  b.q = *(const uint4*)&p[t * 16 + 8];
  float x[16];
#pragma unroll
  for (int j = 0; j < 8; ++j) { x[j] = bf2f(a.u[j]); x[8 + j] = bf2f(b.u[j]); }
  float m = x[0];
#pragma unroll
  for (int j = 1; j < 16; ++j) m = fmaxf(m, x[j]);
  for (int off = 32; off > 0; off >>= 1) m = fmaxf(m, __shfl_xor(m, off));
  __shared__ float redm[4], reds[4];
  if ((t & 63) == 0) redm[t >> 6] = m;
  __syncthreads();
  m = fmaxf(fmaxf(redm[0], redm[1]), fmaxf(redm[2], redm[3]));
  float sum = 0.f;
#pragma unroll
  for (int j = 0; j < 16; ++j) { x[j] = __expf(x[j] - m); sum += x[j]; }
  for (int off = 32; off > 0; off >>= 1) sum += __shfl_xor(sum, off);
  if ((t & 63) == 0) reds[t >> 6] = sum;
  __syncthreads();
  sum = reds[0] + reds[1] + reds[2] + reds[3];
  const float inv = 1.0f / sum;
#pragma unroll
  for (int j = 0; j < 8; ++j) {
    a.u[j] = f2bf(x[j] * inv);
    b.u[j] = f2bf(x[8 + j] * inv);
  }
  *(uint4*)&p[t * 16] = a.q;
  *(uint4*)&p[t * 16 + 8] = b.q;
}

// ---------- ctx partials: split-K x4 over s; bf16 partials (R5 known-good) ----------
__global__ __launch_bounds__(256) void k_ctx(
    const unsigned short* __restrict__ p, const unsigned short* __restrict__ svT,
    const unsigned short* __restrict__ tvT, unsigned short* __restrict__ part) {
  const int b = blockIdx.x >> 1;
  const int m0 = (blockIdx.x & 1) * 64;
  const int n0 = blockIdx.y * 64;
  const int z = blockIdx.z;
  FRAG_VARS;
  __shared__ __align__(16) unsigned short tvl[64 * 72];
  __shared__ __align__(16) unsigned short svl[64 * 24];
  {
    const unsigned short* tvb = tvT + (size_t)b * 32768 + (size_t)n0 * 64;
    const unsigned short* svb = svT + (size_t)b * 32768 + (size_t)n0 * 64 + z * 16;
#pragma unroll
    for (int it = 0; it < 2; ++it) {
      const int idx = tid + it * 256;
      const int r = idx >> 3, c = (idx & 7) * 8;
      *(uint4*)&tvl[r * 72 + c] = *(const uint4*)&tvb[(size_t)r * 64 + c];
    }
    if (tid < 128) {
      const int r = tid >> 1, c = (tid & 1) * 8;
      *(uint4*)&svl[r * 24 + c] = *(const uint4*)&svb[(size_t)r * 64 + c];
    }
  }
  __syncthreads();
  const unsigned short* ar0 =
      p + ((size_t)b * 128 + m0 + mw + fr) * 4096 + z * 1024 + fq * 8;
  const unsigned short* ar1 = ar0 + (size_t)16 * 4096;
  uint4 pa0[4], pa1[4];
#pragma unroll
  for (int i = 0; i < 4; ++i) {
    pa0[i] = *(const uint4*)(ar0 + i * 32);
    pa1[i] = *(const uint4*)(ar1 + i * 32);
  }
#pragma unroll 4
  for (int ks = 0; ks < 32; ++ks) {
    const int sl = ks & 3;
    short8_t av0 = __builtin_bit_cast(short8_t, pa0[sl]);
    short8_t av1 = __builtin_bit_cast(short8_t, pa1[sl]);
    const int kn = ks + 4;
    if (kn < 32) {
      pa0[sl] = *(const uint4*)(ar0 + kn * 32);
      pa1[sl] = *(const uint4*)(ar1 + kn * 32);
    }
    const int s_l = ks >> 1;
    const int t0 = (ks & 1) * 32;
    short8_t tv0 = *(const short8_t*)&tvl[(nw + fr) * 72 + t0 + fq * 8];
    short8_t tv1 = *(const short8_t*)&tvl[(nw + 16 + fr) * 72 + t0 + fq * 8];
    const float sv0 = bf2f(svl[(nw + fr) * 24 + s_l]);
    const float sv1 = bf2f(svl[(nw + 16 + fr) * 24 + s_l]);
    short8_t bv0 = prods8(tv0, sv0);
    short8_t bv1 = prods8(tv1, sv1);
    acc00 = MFMA16(av0, bv0, acc00);
    acc01 = MFMA16(av0, bv1, acc01);
    acc10 = MFMA16(av1, bv0, acc10);
    acc11 = MFMA16(av1, bv1, acc11);
  }
  unsigned short* out = part + ((size_t)z * 2048 + (size_t)b * 128 + m0) * 512 + n0;
  GEMM_EPILOGUE({ out[(size_t)ml * 512 + nl] = f2bf(vv); });
}

// ---------- out = relu(concat(query, sum_z part) @ Wo + bo); K=64, reduce fused ----------
__global__ __launch_bounds__(256) void k_out(
    const unsigned short* __restrict__ query, const unsigned short* __restrict__ part,
    const unsigned short* __restrict__ WoT, const unsigned short* __restrict__ bo,
    void* __restrict__ outv, const void* __restrict__ rawq) {
  __shared__ int shw[4];
  const int f32mode = detect_f32(rawq, threadIdx.x, shw);
  const int m0 = blockIdx.y * 64, n0 = blockIdx.x * 64;
  FRAG_VARS;
  __shared__ __align__(16) unsigned short aL[64 * KPITCH];
  __shared__ __align__(16) unsigned short bL[64 * KPITCH];
  const int r = tid >> 3, c = (tid & 7) * 8;
  const size_t N = (size_t)2048 * 512;
  for (int k0 = 0; k0 < 1536; k0 += 64) {
    uint4 a0v, a1v;
    if (k0 < 1024) {
      a0v = *(const uint4*)&query[(size_t)(m0 + r) * 1024 + k0 + c];
      a1v = *(const uint4*)&query[(size_t)(m0 + r + 32) * 1024 + k0 + c];
    } else {
      const int kk = k0 - 1024;
      float s0[8], s1[8];
#pragma unroll
      for (int j = 0; j < 8; ++j) { s0[j] = 0.f; s1[j] = 0.f; }
#pragma unroll
      for (int z = 0; z < 4; ++z) {
        union { uint4 q; unsigned short u[8]; } t0, t1;
        t0.q = *(const uint4*)&part[z * N + (size_t)(m0 + r) * 512 + kk + c];
        t1.q = *(const uint4*)&part[z * N + (size_t)(m0 + r + 32) * 512 + kk + c];
#pragma unroll
        for (int j = 0; j < 8; ++j) { s0[j] += bf2f(t0.u[j]); s1[j] += bf2f(t1.u[j]); }
      }
      union { uint4 q; unsigned short u[8]; } o0, o1;
#pragma unroll
      for (int j = 0; j < 8; ++j) { o0.u[j] = f2bf(s0[j]); o1.u[j] = f2bf(s1[j]); }
      a0v = o0.q; a1v = o1.q;
    }
    uint4 b0v = *(const uint4*)&WoT[(size_t)(n0 + r) * 1536 + k0 + c];
    uint4 b1v = *(const uint4*)&WoT[(size_t)(n0 + r + 32) * 1536 + k0 + c];
    __syncthreads();
    *(uint4*)&aL[r * KPITCH + c] = a0v;
    *(uint4*)&aL[(r + 32) * KPITCH + c] = a1v;
    *(uint4*)&bL[r * KPITCH + c] = b0v;
    *(uint4*)&bL[(r + 32) * KPITCH + c] = b1v;
    __syncthreads();
    MFMA_K32(aL, bL, fq * 8);
    MFMA_K32(aL, bL, 32 + fq * 8);
  }
  GEMM_EPILOGUE({
    float v = fmaxf(vv + bf2f(bo[n0 + nl]), 0.f);
    const size_t idx = (size_t)(m0 + ml) * 512 + n0 + nl;
    if (f32mode)
      ((float*)outv)[idx] = v;
    else
      ((unsigned short*)outv)[idx] = f2bf(v);
  });
}

// ---------- launch ----------
extern "C" void kernel_launch(void* const* d_in, const int* in_sizes, int n_in,
                              void* d_out, int out_size, void* d_ws, size_t ws_size,
                              hipStream_t stream) {
  const void* query = d_in[0];
  const void* src = d_in[1];
  const void* trg = d_in[2];
  const void* Wq = d_in[3];
  const void* bq = d_in[4];
  const void* Ws = d_in[5];
  const void* bs = d_in[6];
  const void* Wt = d_in[7];
  const void* bt = d_in[8];
  const void* Wsv = d_in[9];
  const void* bsv = d_in[10];
  const void* Wtv = d_in[11];
  const void* btv = d_in[12];
  const void* Wo = d_in[13];
  const void* bo = d_in[14];

  char* ws = (char*)d_ws;
  size_t off = 0;
  auto alloc = [&](size_t bytes) {
    char* ptr = ws + off;
    off = (off + bytes + 255) & ~(size_t)255;
    return ptr;
  };
  unsigned short* qc = (unsigned short*)alloc((size_t)2048 * 1024 * 2);
  unsigned short* srcc = (unsigned short*)alloc((size_t)1024 * 1024 * 2);
  unsigned short* trgc = (unsigned short*)alloc((size_t)1024 * 1024 * 2);
  unsigned short* biasc = (unsigned short*)alloc((size_t)6 * 512 * 2);
  unsigned short* wT = (unsigned short*)alloc((size_t)5 * 524288 * 2);
  unsigned short* woT = (unsigned short*)alloc((size_t)512 * 1536 * 2);
  unsigned short* q_s = (unsigned short*)alloc((size_t)2048 * 512 * 2);
  unsigned short* s_key = (unsigned short*)alloc((size_t)1024 * 512 * 2);
  unsigned short* t_key = (unsigned short*)alloc((size_t)1024 * 512 * 2);
  unsigned short* sv_T = (unsigned short*)alloc((size_t)16 * 512 * 64 * 2);
  unsigned short* tv_T = (unsigned short*)alloc((size_t)16 * 512 * 64 * 2);
  unsigned short* scores = (unsigned short*)alloc((size_t)2048 * 4096 * 2);
  unsigned short* part = (unsigned short*)alloc((size_t)4 * 2048 * 512 * 2);
  (void)ws_size; (void)in_sizes; (void)n_in; (void)out_size;

  PrepArgs pr;
  pr.csrc[0] = query; pr.csrc[1] = src; pr.csrc[2] = trg;
  pr.csrc[3] = bq; pr.csrc[4] = bs; pr.csrc[5] = bt;
  pr.csrc[6] = bsv; pr.csrc[7] = btv; pr.csrc[8] = bo;
  pr.cdst[0] = qc; pr.cdst[1] = srcc; pr.cdst[2] = trgc;
  for (int i = 0; i < 6; ++i) pr.cdst[3 + i] = biasc + i * 512;
  pr.cn[0] = 2048 * 1024; pr.cn[1] = 1024 * 1024; pr.cn[2] = 1024 * 1024;
  for (int i = 0; i < 6; ++i) pr.cn[3 + i] = 512;
  pr.tsrc[0] = Wq; pr.tsrc[1] = Ws; pr.tsrc[2] = Wt;
  pr.tsrc[3] = Wsv; pr.tsrc[4] = Wtv; pr.tsrc[5] = Wo;
  for (int i = 0; i < 5; ++i) { pr.tdst[i] = wT + (size_t)i * 524288; pr.tK[i] = 1024; }
  pr.tdst[5] = woT; pr.tK[5] = 1536;
  hipLaunchKernelGGL(k_prep, dim3(16, 48, 15), dim3(256), 0, stream, pr);

  ProjArgs pa;
  pa.A[0] = qc; pa.A[1] = srcc; pa.A[2] = trgc; pa.A[3] = srcc; pa.A[4] = trgc;
  for (int i = 0; i < 5; ++i) pa.W[i] = wT + (size_t)i * 524288;
  for (int i = 0; i < 5; ++i) pa.bias[i] = biasc + i * 512;
  pa.out[0] = q_s; pa.out[1] = s_key; pa.out[2] = t_key; pa.out[3] = sv_T; pa.out[4] = tv_T;
  hipLaunchKernelGGL(k_proj, dim3(768), dim3(256), 0, stream, pa);

  hipLaunchKernelGGL(k_scores, dim3(32, 2, 16), dim3(256), 0, stream, q_s, s_key, t_key, scores);
  hipLaunchKernelGGL(k_softmax, dim3(2048), dim3(256), 0, stream, scores);
  hipLaunchKernelGGL(k_ctx, dim3(32, 8, 4), dim3(256), 0, stream, scores, sv_T, tv_T, part);
  hipLaunchKernelGGL(k_out, dim3(8, 32, 1), dim3(256), 0, stream, qc, part, woT,
                     biasc + 5 * 512, d_out, query);
}

// Round 11
// 207.921 us; speedup vs baseline: 1.0923x; 1.0119x over previous
//
#include <hip/hip_runtime.h>
#include <cstdint>

// ---------- types & helpers ----------
typedef __attribute__((ext_vector_type(8))) short short8_t;
typedef __attribute__((ext_vector_type(8))) __bf16 bf16x8_t;
typedef __attribute__((ext_vector_type(4))) float f32x4_t;

__device__ __forceinline__ float bf2f(unsigned short u) {
  return __uint_as_float(((unsigned)u) << 16);
}
__device__ __forceinline__ unsigned short f2bf(float f) {  // RNE
  unsigned u = __float_as_uint(f);
  u += 0x7FFFu + ((u >> 16) & 1u);
  return (unsigned short)(u >> 16);
}

// MFMA wrapper: tolerate either builtin signature (short8 or bf16x8 operands).
template <typename V>
__device__ __forceinline__ auto mfma16_impl(V a, V b, f32x4_t c, int)
    -> decltype(__builtin_amdgcn_mfma_f32_16x16x32_bf16(a, b, c, 0, 0, 0)) {
  return __builtin_amdgcn_mfma_f32_16x16x32_bf16(a, b, c, 0, 0, 0);
}
template <typename V>
__device__ __forceinline__ f32x4_t mfma16_impl(V a, V b, f32x4_t c, long) {
  bf16x8_t ab = __builtin_bit_cast(bf16x8_t, a);
  bf16x8_t bb = __builtin_bit_cast(bf16x8_t, b);
  return __builtin_amdgcn_mfma_f32_16x16x32_bf16(ab, bb, c, 0, 0, 0);
}
__device__ __forceinline__ f32x4_t MFMA16(short8_t a, short8_t b, f32x4_t c) {
  return mfma16_impl(a, b, c, 0);
}

#define KPITCH 72   // 64-col K-tiles padded to 72 (k_out)

#define FRAG_VARS                                                       \
  const int tid = threadIdx.x;                                          \
  const int lane = tid & 63;                                            \
  const int wv = tid >> 6;                                              \
  const int mw = (wv >> 1) << 5;                                        \
  const int nw = (wv & 1) << 5;                                         \
  const int fr = lane & 15;                                             \
  const int fq = lane >> 4;                                             \
  f32x4_t acc00 = {0.f, 0.f, 0.f, 0.f};                                 \
  f32x4_t acc01 = acc00, acc10 = acc00, acc11 = acc00;

// Body sees: ml (local m), nl (local n), vv (float value). Variadic for commas.
#define GEMM_EPILOGUE(...)                                              \
  {                                                                     \
    const f32x4_t accs_[4] = {acc00, acc01, acc10, acc11};              \
    _Pragma("unroll") for (int im_ = 0; im_ < 2; ++im_)                 \
    _Pragma("unroll") for (int jn_ = 0; jn_ < 2; ++jn_) {               \
      f32x4_t aa_ = accs_[im_ * 2 + jn_];                               \
      const int ml0_ = mw + im_ * 16 + fq * 4;                          \
      const int nl = nw + jn_ * 16 + fr;                                \
      _Pragma("unroll") for (int r_ = 0; r_ < 4; ++r_) {                \
        const int ml = ml0_ + r_;                                       \
        const float vv = aa_[r_];                                       \
        __VA_ARGS__;                                                    \
      }                                                                 \
    }                                                                   \
  }

// MFMA group for one 32-wide k-slice read from KPITCH LDS tiles (k_out).
#define MFMA_K32(aLbuf, bLbuf, kf)                                      \
  do {                                                                  \
    short8_t a0_ = *(const short8_t*)&aLbuf[(mw + fr) * KPITCH + (kf)]; \
    short8_t a1_ = *(const short8_t*)&aLbuf[(mw + 16 + fr) * KPITCH + (kf)]; \
    short8_t b0_ = *(const short8_t*)&bLbuf[(nw + fr) * KPITCH + (kf)]; \
    short8_t b1_ = *(const short8_t*)&bLbuf[(nw + 16 + fr) * KPITCH + (kf)]; \
    acc00 = MFMA16(a0_, b0_, acc00);                                    \
    acc01 = MFMA16(a0_, b1_, acc01);                                    \
    acc10 = MFMA16(a1_, b0_, acc10);                                    \
    acc11 = MFMA16(a1_, b1_, acc11);                                    \
  } while (0)

// ---------- async 16B/lane global->LDS (dest = wave-uniform base + lane*16) ----------
#if __has_builtin(__builtin_amdgcn_global_load_lds)
__device__ __forceinline__ void gload16(const void* g, void* lds_wave_base) {
  __builtin_amdgcn_global_load_lds(g, lds_wave_base, 16, 0, 0);
}
#else
__device__ __forceinline__ void gload16(const void* g, void* lds_wave_base) {
  const int lane = threadIdx.x & 63;  // synchronous fallback, same slot mapping
  ((uint4*)lds_wave_base)[lane] = *(const uint4*)g;
}
#endif

// ---------- inline dtype detector (per-block, deterministic, L2-broadcast) ----------
__device__ __forceinline__ int detect_f32(const void* q, int tid, int* sh) {
  const unsigned short* p = (const unsigned short*)q;
  int w = 0;
  for (int i = tid; i < 512; i += 256) {
    float v = bf2f(p[i]);
    float av = fabsf(v);
    if (!(av <= 1e4f) || (v != 0.f && av < 1e-10f)) ++w;  // NaN fails av<=1e4
  }
#pragma unroll
  for (int off = 32; off > 0; off >>= 1) w += __shfl_xor(w, off);
  if ((tid & 63) == 0) sh[tid >> 6] = w;
  __syncthreads();
  return (sh[0] + sh[1] + sh[2] + sh[3]) > 40;  // 1 = inputs are f32
}

// ---------- merged prep: convert (z<9) + weight transpose (z>=9), vectorized ----------
struct PrepArgs {
  const void* csrc[9];
  unsigned short* cdst[9];
  int cn[9];
  const void* tsrc[6];
  unsigned short* tdst[6];
  int tK[6];
};

__global__ __launch_bounds__(256) void k_prep(PrepArgs a) {
  __shared__ int shw[4];
  __shared__ unsigned short t[32][33];
  const int f32mode = detect_f32(a.csrc[0], threadIdx.x, shw);
  const int z = blockIdx.z;
  if (z < 9) {
    const int n = a.cn[z];  // all n divisible by 8
    const int bid = blockIdx.y * 16 + blockIdx.x;  // 0..767
    const int stride = 768 * 256;
    if (f32mode) {
      const float4* s4 = (const float4*)a.csrc[z];
      ushort4* d4 = (ushort4*)a.cdst[z];
      const int n4 = n >> 2;
      for (int i = bid * 256 + threadIdx.x; i < n4; i += stride) {
        float4 v = s4[i];
        ushort4 o;
        o.x = f2bf(v.x); o.y = f2bf(v.y); o.z = f2bf(v.z); o.w = f2bf(v.w);
        d4[i] = o;
      }
    } else {
      const uint4* s8 = (const uint4*)a.csrc[z];
      uint4* d8 = (uint4*)a.cdst[z];
      const int n8 = n >> 3;
      for (int i = bid * 256 + threadIdx.x; i < n8; i += stride) d8[i] = s8[i];
    }
  } else {
    const int w = z - 9;
    const int K = a.tK[w];
    const int k0 = blockIdx.y * 32, n0 = blockIdx.x * 32;
    if (k0 >= K) return;
    const int r = threadIdx.x >> 3;        // 0..31
    const int c4 = (threadIdx.x & 7) * 4;  // 0,4,..,28
    if (f32mode) {
      const float* s = (const float*)a.tsrc[w];
      float4 v = *(const float4*)&s[(size_t)(k0 + r) * 512 + n0 + c4];
      t[r][c4] = f2bf(v.x); t[r][c4 + 1] = f2bf(v.y);
      t[r][c4 + 2] = f2bf(v.z); t[r][c4 + 3] = f2bf(v.w);
    } else {
      const unsigned short* s = (const unsigned short*)a.tsrc[w];
      ushort4 v = *(const ushort4*)&s[(size_t)(k0 + r) * 512 + n0 + c4];
      t[r][c4] = v.x; t[r][c4 + 1] = v.y; t[r][c4 + 2] = v.z; t[r][c4 + 3] = v.w;
    }
    __syncthreads();
    unsigned short* d = a.tdst[w];
    ushort4 o;
    o.x = t[c4][r]; o.y = t[c4 + 1][r]; o.z = t[c4 + 2][r]; o.w = t[c4 + 3][r];
    *(ushort4*)&d[(size_t)(n0 + r) * K + k0 + c4] = o;
  }
}

// ---------- five projections: async global_load_lds, dbuf, XOR-swizzled LDS (R9 good) ----------
struct ProjArgs {
  const unsigned short* A[5];
  const unsigned short* W[5];
  const unsigned short* bias[5];
  unsigned short* out[5];
};

__global__ __launch_bounds__(256) void k_proj(ProjArgs args) {
  const int id = blockIdx.x;  // 0..767, all live
  int op, by, bx;
  if (id < 256) {
    op = 0; by = id >> 3; bx = id & 7;
  } else {
    int r2 = id - 256;
    op = 1 + (r2 >> 7); r2 &= 127; by = r2 >> 3; bx = r2 & 7;
  }
  const int m0 = by * 64, n0 = bx * 64;
  const unsigned short* A = args.A[op];
  const unsigned short* W = args.W[op];
  FRAG_VARS;
  __shared__ __align__(16) unsigned short sm[2][2][64 * 64];  // [buf][A=0/B=1] 32KB
  const int srow = lane >> 3;                       // 0..7 within wave's 8 rows
  const int scol = ((lane & 7) ^ srow) * 8;         // swizzled global elem offset
#pragma unroll
  for (int h = 0; h < 2; ++h) {
    const int row = h * 32 + wv * 8;
    gload16(&A[(size_t)(m0 + row + srow) * 1024 + scol], &sm[0][0][row * 64]);
    gload16(&W[(size_t)(n0 + row + srow) * 1024 + scol], &sm[0][1][row * 64]);
  }
  const int cs0 = ((fq) ^ (fr & 7)) * 8;        // ks=0 slot
  const int cs1 = ((4 + fq) ^ (fr & 7)) * 8;    // ks=1 slot
  for (int kc = 0; kc < 16; ++kc) {
    const int cur = kc & 1;
    __syncthreads();
    if (kc + 1 < 16) {
      const int nxt = cur ^ 1;
      const int k0 = (kc + 1) * 64;
#pragma unroll
      for (int h = 0; h < 2; ++h) {
        const int row = h * 32 + wv * 8;
        gload16(&A[(size_t)(m0 + row + srow) * 1024 + k0 + scol], &sm[nxt][0][row * 64]);
        gload16(&W[(size_t)(n0 + row + srow) * 1024 + k0 + scol], &sm[nxt][1][row * 64]);
      }
    }
    const unsigned short* Ab = sm[cur][0];
    const unsigned short* Bb = sm[cur][1];
    {
      short8_t a0 = *(const short8_t*)&Ab[(mw + fr) * 64 + cs0];
      short8_t a1 = *(const short8_t*)&Ab[(mw + 16 + fr) * 64 + cs0];
      short8_t b0 = *(const short8_t*)&Bb[(nw + fr) * 64 + cs0];
      short8_t b1 = *(const short8_t*)&Bb[(nw + 16 + fr) * 64 + cs0];
      acc00 = MFMA16(a0, b0, acc00);
      acc01 = MFMA16(a0, b1, acc01);
      acc10 = MFMA16(a1, b0, acc10);
      acc11 = MFMA16(a1, b1, acc11);
    }
    {
      short8_t a0 = *(const short8_t*)&Ab[(mw + fr) * 64 + cs1];
      short8_t a1 = *(const short8_t*)&Ab[(mw + 16 + fr) * 64 + cs1];
      short8_t b0 = *(const short8_t*)&Bb[(nw + fr) * 64 + cs1];
      short8_t b1 = *(const short8_t*)&Bb[(nw + 16 + fr) * 64 + cs1];
      acc00 = MFMA16(a0, b0, acc00);
      acc01 = MFMA16(a0, b1, acc01);
      acc10 = MFMA16(a1, b0, acc10);
      acc11 = MFMA16(a1, b1, acc11);
    }
  }
  const float scale = (op == 0) ? 0.044194173824159216f : 1.0f;
  const unsigned short* bias = args.bias[op];
  unsigned short* out = args.out[op];
  GEMM_EPILOGUE({
    const float v = (vv + bf2f(bias[n0 + nl])) * scale;
    const int m = m0 + ml;
    const int n = n0 + nl;
    if (op < 3) {
      out[(size_t)m * 512 + n] = f2bf(v);
    } else {
      const int bb = m >> 6;
      const int ss = m & 63;
      out[(size_t)bb * 32768 + (size_t)n * 64 + ss] = f2bf(v);
    }
  });
}

// ---------- scores: async dbuf staging, 64-k chunks (R10 known-good) ----------
__global__ __launch_bounds__(256) void k_scores(
    const unsigned short* __restrict__ qs, const unsigned short* __restrict__ skey,
    const unsigned short* __restrict__ tkey, unsigned short* __restrict__ scores) {
  const int b = blockIdx.z;
  const int m0 = blockIdx.y * 64;
  const int sx = blockIdx.x;  // s = sx*2 + {0,1}
  const int tid = threadIdx.x;
  const int lane = tid & 63;
  const int wv = tid >> 6;
  const int mw = (wv >> 1) << 5;
  const int nw = (wv & 1) << 5;
  const int fr = lane & 15;
  const int fq = lane >> 4;
  __shared__ __align__(16) unsigned short qS[2][64 * 64];   // 16KB
  __shared__ __align__(16) unsigned short tkS[2][64 * 64];  // 16KB
  __shared__ __align__(16) unsigned short skL[1024];        // 2KB: 2 s-rows x 512
  f32x4_t acc[2][4];
#pragma unroll
  for (int s = 0; s < 2; ++s)
#pragma unroll
    for (int i = 0; i < 4; ++i) acc[s][i] = (f32x4_t){0.f, 0.f, 0.f, 0.f};
  const unsigned short* qb = qs + ((size_t)b * 128 + m0) * 512;
  const unsigned short* tkb = tkey + (size_t)b * 64 * 512;
  const unsigned short* skb = skey + ((size_t)b * 64 + sx * 2) * 512;
  if (tid < 128) *(uint4*)&skL[tid * 8] = *(const uint4*)&skb[tid * 8];
  const int srow = lane >> 3;
  const int scol = ((lane & 7) ^ srow) * 8;
#pragma unroll
  for (int h = 0; h < 2; ++h) {
    const int row = h * 32 + wv * 8;
    gload16(&qb[(size_t)(row + srow) * 512 + scol], &qS[0][row * 64]);
    gload16(&tkb[(size_t)(row + srow) * 512 + scol], &tkS[0][row * 64]);
  }
  const int cs0 = ((fq) ^ (fr & 7)) * 8;
  const int cs1 = ((4 + fq) ^ (fr & 7)) * 8;
  for (int kc = 0; kc < 8; ++kc) {
    const int cur = kc & 1;
    __syncthreads();  // drains prev prefetch (overlapped with prev compute)
    if (kc + 1 < 8) {
      const int k0 = (kc + 1) * 64;
      const int nxt = cur ^ 1;
#pragma unroll
      for (int h = 0; h < 2; ++h) {
        const int row = h * 32 + wv * 8;
        gload16(&qb[(size_t)(row + srow) * 512 + k0 + scol], &qS[nxt][row * 64]);
        gload16(&tkb[(size_t)(row + srow) * 512 + k0 + scol], &tkS[nxt][row * 64]);
      }
    }
#pragma unroll
    for (int ks = 0; ks < 2; ++ks) {
      const int cs = ks ? cs1 : cs0;
      short8_t a0 = *(const short8_t*)&qS[cur][(mw + fr) * 64 + cs];
      short8_t a1 = *(const short8_t*)&qS[cur][(mw + 16 + fr) * 64 + cs];
      uint4 tq[2];
      tq[0] = *(const uint4*)&tkS[cur][(nw + fr) * 64 + cs];
      tq[1] = *(const uint4*)&tkS[cur][(nw + 16 + fr) * 64 + cs];
      float tlo[2][4], thi[2][4];
#pragma unroll
      for (int h = 0; h < 2; ++h) {
        const unsigned* tw = (const unsigned*)&tq[h];
#pragma unroll
        for (int j = 0; j < 4; ++j) {
          tlo[h][j] = __uint_as_float(tw[j] << 16);
          thi[h][j] = __uint_as_float(tw[j] & 0xffff0000u);
        }
      }
      const int koff = kc * 64 + ks * 32 + fq * 8;  // logical k for sk (broadcast)
#pragma unroll
      for (int s = 0; s < 2; ++s) {
        uint4 skq = *(const uint4*)&skL[s * 512 + koff];
        const unsigned* sw = (const unsigned*)&skq;
        union { short8_t v; unsigned w[4]; } b0, b1;
#pragma unroll
        for (int j = 0; j < 4; ++j) {
          const float slo = __uint_as_float(sw[j] << 16);
          const float shi = __uint_as_float(sw[j] & 0xffff0000u);
          b0.w[j] = __builtin_amdgcn_perm(__float_as_uint(thi[0][j] * shi),
                                          __float_as_uint(tlo[0][j] * slo), 0x07060302);
          b1.w[j] = __builtin_amdgcn_perm(__float_as_uint(thi[1][j] * shi),
                                          __float_as_uint(tlo[1][j] * slo), 0x07060302);
        }
        acc[s][0] = MFMA16(a0, b0.v, acc[s][0]);
        acc[s][1] = MFMA16(a0, b1.v, acc[s][1]);
        acc[s][2] = MFMA16(a1, b0.v, acc[s][2]);
        acc[s][3] = MFMA16(a1, b1.v, acc[s][3]);
      }
    }
  }
#pragma unroll
  for (int s = 0; s < 2; ++s) {
    unsigned short* out = scores + ((size_t)b * 128 + m0) * 4096 + (size_t)(sx * 2 + s) * 64;
#pragma unroll
    for (int im = 0; im < 2; ++im)
#pragma unroll
      for (int jn = 0; jn < 2; ++jn) {
        f32x4_t aa = acc[s][im * 2 + jn];
        const int col = nw + jn * 16 + fr;
#pragma unroll
        for (int r = 0; r < 4; ++r) {
          const int row = mw + im * 16 + fq * 4 + r;
          out[(size_t)row * 4096 + col] = f2bf(aa[r]);
        }
      }
  }
}

// ---------- in-place softmax over each row of 4096 ----------
__global__ __launch_bounds__(256) void k_softmax(unsigned short* __restrict__ s) {
  unsigned short* p = s + (size_t)blockIdx.x * 4096;
  const int t = threadIdx.x;
  union U8 { uint4 q; unsigned short u[8]; };
  U8 a, b;
  a.q = *(const uint4*)&p[t * 16];
  b.q = *(const uint4*)&p[t * 16 + 8];
  float x[16];
#pragma unroll
  for (int j = 0; j < 8; ++j) { x[j] = bf2f(a.u[j]); x[8 + j] = bf2f(b.u[j]); }
  float m = x[0];
#pragma unroll
  for (int j = 1; j < 16; ++j) m = fmaxf(m, x[j]);
  for (int off = 32; off > 0; off >>= 1) m = fmaxf(m, __shfl_xor(m, off));
  __shared__ float redm[4], reds[4];
  if ((t & 63) == 0) redm[t >> 6] = m;
  __syncthreads();
  m = fmaxf(fmaxf(redm[0], redm[1]), fmaxf(redm[2], redm[3]));
  float sum = 0.f;
#pragma unroll
  for (int j = 0; j < 16; ++j) { x[j] = __expf(x[j] - m); sum += x[j]; }
  for (int off = 32; off > 0; off >>= 1) sum += __shfl_xor(sum, off);
  if ((t & 63) == 0) reds[t >> 6] = sum;
  __syncthreads();
  sum = reds[0] + reds[1] + reds[2] + reds[3];
  const float inv = 1.0f / sum;
#pragma unroll
  for (int j = 0; j < 8; ++j) {
    a.u[j] = f2bf(x[j] * inv);
    b.u[j] = f2bf(x[8 + j] * inv);
  }
  *(uint4*)&p[t * 16] = a.q;
  *(uint4*)&p[t * 16 + 8] = b.q;
}

// ---------- ctx partials: s-factored, no repack ----------
// ctx[l,ch] = sum_s sv[ch,s] * (sum_t p[l,st] * tvT[ch,t]).  Per s: M = p_s @ tv
// (raw bf16 fragments, tv loop-invariant), then ctx += sv (x) M in fp32 VALU.
__global__ __launch_bounds__(256) void k_ctx(
    const unsigned short* __restrict__ p, const unsigned short* __restrict__ svT,
    const unsigned short* __restrict__ tvT, unsigned short* __restrict__ part) {
  const int b = blockIdx.x >> 1;
  const int m0 = (blockIdx.x & 1) * 64;
  const int n0 = blockIdx.y * 64;
  const int z = blockIdx.z;  // s-chunk: s in [z*16, z*16+16)
  FRAG_VARS;
  __shared__ __align__(16) unsigned short tvl[64 * 72];
  __shared__ __align__(16) unsigned short svl[64 * 24];
  {
    const unsigned short* tvb = tvT + (size_t)b * 32768 + (size_t)n0 * 64;
    const unsigned short* svb = svT + (size_t)b * 32768 + (size_t)n0 * 64 + z * 16;
#pragma unroll
    for (int it = 0; it < 2; ++it) {
      const int idx = tid + it * 256;
      const int r = idx >> 3, c = (idx & 7) * 8;
      *(uint4*)&tvl[r * 72 + c] = *(const uint4*)&tvb[(size_t)r * 64 + c];
    }
    if (tid < 128) {
      const int r = tid >> 1, c = (tid & 1) * 8;
      *(uint4*)&svl[r * 24 + c] = *(const uint4*)&svb[(size_t)r * 64 + c];
    }
  }
  __syncthreads();
  // Loop-invariant B fragments (raw tv): [jn][kstep]
  short8_t bv[2][2];
  bv[0][0] = *(const short8_t*)&tvl[(nw + fr) * 72 + fq * 8];
  bv[0][1] = *(const short8_t*)&tvl[(nw + fr) * 72 + 32 + fq * 8];
  bv[1][0] = *(const short8_t*)&tvl[(nw + 16 + fr) * 72 + fq * 8];
  bv[1][1] = *(const short8_t*)&tvl[(nw + 16 + fr) * 72 + 32 + fq * 8];
  // A stream (p rows), depth-2 register prefetch: [slot][row-tile][kstep]
  const unsigned short* ar0 =
      p + ((size_t)b * 128 + m0 + mw + fr) * 4096 + z * 1024 + fq * 8;
  const unsigned short* ar1 = ar0 + (size_t)16 * 4096;
  uint4 pa[2][2][2];
#pragma unroll
  for (int d = 0; d < 2; ++d) {
    pa[d][0][0] = *(const uint4*)(ar0 + d * 64);
    pa[d][0][1] = *(const uint4*)(ar0 + d * 64 + 32);
    pa[d][1][0] = *(const uint4*)(ar1 + d * 64);
    pa[d][1][1] = *(const uint4*)(ar1 + d * 64 + 32);
  }
#pragma unroll 2
  for (int s = 0; s < 16; ++s) {
    const int sl = s & 1;
    short8_t a00 = __builtin_bit_cast(short8_t, pa[sl][0][0]);
    short8_t a01 = __builtin_bit_cast(short8_t, pa[sl][0][1]);
    short8_t a10 = __builtin_bit_cast(short8_t, pa[sl][1][0]);
    short8_t a11 = __builtin_bit_cast(short8_t, pa[sl][1][1]);
    if (s + 2 < 16) {
      const int off = (s + 2) * 64;
      pa[sl][0][0] = *(const uint4*)(ar0 + off);
      pa[sl][0][1] = *(const uint4*)(ar0 + off + 32);
      pa[sl][1][0] = *(const uint4*)(ar1 + off);
      pa[sl][1][1] = *(const uint4*)(ar1 + off + 32);
    }
    const f32x4_t z4 = {0.f, 0.f, 0.f, 0.f};
    f32x4_t M00 = MFMA16(a00, bv[0][0], z4);
    M00 = MFMA16(a01, bv[0][1], M00);
    f32x4_t M01 = MFMA16(a00, bv[1][0], z4);
    M01 = MFMA16(a01, bv[1][1], M01);
    f32x4_t M10 = MFMA16(a10, bv[0][0], z4);
    M10 = MFMA16(a11, bv[0][1], M10);
    f32x4_t M11 = MFMA16(a10, bv[1][0], z4);
    M11 = MFMA16(a11, bv[1][1], M11);
    const float sv0 = bf2f(svl[(nw + fr) * 24 + s]);
    const float sv1 = bf2f(svl[(nw + 16 + fr) * 24 + s]);
#pragma unroll
    for (int r = 0; r < 4; ++r) {
      acc00[r] += sv0 * M00[r];
      acc01[r] += sv1 * M01[r];
      acc10[r] += sv0 * M10[r];
      acc11[r] += sv1 * M11[r];
    }
  }
  unsigned short* out = part + ((size_t)z * 2048 + (size_t)b * 128 + m0) * 512 + n0;
  GEMM_EPILOGUE({ out[(size_t)ml * 512 + nl] = f2bf(vv); });
}

// ---------- out = relu(concat(query, sum_z part) @ Wo + bo); K=64, reduce fused ----------
__global__ __launch_bounds__(256) void k_out(
    const unsigned short* __restrict__ query, const unsigned short* __restrict__ part,
    const unsigned short* __restrict__ WoT, const unsigned short* __restrict__ bo,
    void* __restrict__ outv, const void* __restrict__ rawq) {
  __shared__ int shw[4];
  const int f32mode = detect_f32(rawq, threadIdx.x, shw);
  const int m0 = blockIdx.y * 64, n0 = blockIdx.x * 64;
  FRAG_VARS;
  __shared__ __align__(16) unsigned short aL[64 * KPITCH];
  __shared__ __align__(16) unsigned short bL[64 * KPITCH];
  const int r = tid >> 3, c = (tid & 7) * 8;
  const size_t N = (size_t)2048 * 512;
  for (int k0 = 0; k0 < 1536; k0 += 64) {
    uint4 a0v, a1v;
    if (k0 < 1024) {
      a0v = *(const uint4*)&query[(size_t)(m0 + r) * 1024 + k0 + c];
      a1v = *(const uint4*)&query[(size_t)(m0 + r + 32) * 1024 + k0 + c];
    } else {
      const int kk = k0 - 1024;
      float s0[8], s1[8];
#pragma unroll
      for (int j = 0; j < 8; ++j) { s0[j] = 0.f; s1[j] = 0.f; }
#pragma unroll
      for (int z = 0; z < 4; ++z) {
        union { uint4 q; unsigned short u[8]; } t0, t1;
        t0.q = *(const uint4*)&part[z * N + (size_t)(m0 + r) * 512 + kk + c];
        t1.q = *(const uint4*)&part[z * N + (size_t)(m0 + r + 32) * 512 + kk + c];
#pragma unroll
        for (int j = 0; j < 8; ++j) { s0[j] += bf2f(t0.u[j]); s1[j] += bf2f(t1.u[j]); }
      }
      union { uint4 q; unsigned short u[8]; } o0, o1;
#pragma unroll
      for (int j = 0; j < 8; ++j) { o0.u[j] = f2bf(s0[j]); o1.u[j] = f2bf(s1[j]); }
      a0v = o0.q; a1v = o1.q;
    }
    uint4 b0v = *(const uint4*)&WoT[(size_t)(n0 + r) * 1536 + k0 + c];
    uint4 b1v = *(const uint4*)&WoT[(size_t)(n0 + r + 32) * 1536 + k0 + c];
    __syncthreads();
    *(uint4*)&aL[r * KPITCH + c] = a0v;
    *(uint4*)&aL[(r + 32) * KPITCH + c] = a1v;
    *(uint4*)&bL[r * KPITCH + c] = b0v;
    *(uint4*)&bL[(r + 32) * KPITCH + c] = b1v;
    __syncthreads();
    MFMA_K32(aL, bL, fq * 8);
    MFMA_K32(aL, bL, 32 + fq * 8);
  }
  GEMM_EPILOGUE({
    float v = fmaxf(vv + bf2f(bo[n0 + nl]), 0.f);
    const size_t idx = (size_t)(m0 + ml) * 512 + n0 + nl;
    if (f32mode)
      ((float*)outv)[idx] = v;
    else
      ((unsigned short*)outv)[idx] = f2bf(v);
  });
}

// ---------- launch ----------
extern "C" void kernel_launch(void* const* d_in, const int* in_sizes, int n_in,
                              void* d_out, int out_size, void* d_ws, size_t ws_size,
                              hipStream_t stream) {
  const void* query = d_in[0];
  const void* src = d_in[1];
  const void* trg = d_in[2];
  const void* Wq = d_in[3];
  const void* bq = d_in[4];
  const void* Ws = d_in[5];
  const void* bs = d_in[6];
  const void* Wt = d_in[7];
  const void* bt = d_in[8];
  const void* Wsv = d_in[9];
  const void* bsv = d_in[10];
  const void* Wtv = d_in[11];
  const void* btv = d_in[12];
  const void* Wo = d_in[13];
  const void* bo = d_in[14];

  char* ws = (char*)d_ws;
  size_t off = 0;
  auto alloc = [&](size_t bytes) {
    char* ptr = ws + off;
    off = (off + bytes + 255) & ~(size_t)255;
    return ptr;
  };
  unsigned short* qc = (unsigned short*)alloc((size_t)2048 * 1024 * 2);
  unsigned short* srcc = (unsigned short*)alloc((size_t)1024 * 1024 * 2);
  unsigned short* trgc = (unsigned short*)alloc((size_t)1024 * 1024 * 2);
  unsigned short* biasc = (unsigned short*)alloc((size_t)6 * 512 * 2);
  unsigned short* wT = (unsigned short*)alloc((size_t)5 * 524288 * 2);
  unsigned short* woT = (unsigned short*)alloc((size_t)512 * 1536 * 2);
  unsigned short* q_s = (unsigned short*)alloc((size_t)2048 * 512 * 2);
  unsigned short* s_key = (unsigned short*)alloc((size_t)1024 * 512 * 2);
  unsigned short* t_key = (unsigned short*)alloc((size_t)1024 * 512 * 2);
  unsigned short* sv_T = (unsigned short*)alloc((size_t)16 * 512 * 64 * 2);
  unsigned short* tv_T = (unsigned short*)alloc((size_t)16 * 512 * 64 * 2);
  unsigned short* scores = (unsigned short*)alloc((size_t)2048 * 4096 * 2);
  unsigned short* part = (unsigned short*)alloc((size_t)4 * 2048 * 512 * 2);
  (void)ws_size; (void)in_sizes; (void)n_in; (void)out_size;

  PrepArgs pr;
  pr.csrc[0] = query; pr.csrc[1] = src; pr.csrc[2] = trg;
  pr.csrc[3] = bq; pr.csrc[4] = bs; pr.csrc[5] = bt;
  pr.csrc[6] = bsv; pr.csrc[7] = btv; pr.csrc[8] = bo;
  pr.cdst[0] = qc; pr.cdst[1] = srcc; pr.cdst[2] = trgc;
  for (int i = 0; i < 6; ++i) pr.cdst[3 + i] = biasc + i * 512;
  pr.cn[0] = 2048 * 1024; pr.cn[1] = 1024 * 1024; pr.cn[2] = 1024 * 1024;
  for (int i = 0; i < 6; ++i) pr.cn[3 + i] = 512;
  pr.tsrc[0] = Wq; pr.tsrc[1] = Ws; pr.tsrc[2] = Wt;
  pr.tsrc[3] = Wsv; pr.tsrc[4] = Wtv; pr.tsrc[5] = Wo;
  for (int i = 0; i < 5; ++i) { pr.tdst[i] = wT + (size_t)i * 524288; pr.tK[i] = 1024; }
  pr.tdst[5] = woT; pr.tK[5] = 1536;
  hipLaunchKernelGGL(k_prep, dim3(16, 48, 15), dim3(256), 0, stream, pr);

  ProjArgs pa;
  pa.A[0] = qc; pa.A[1] = srcc; pa.A[2] = trgc; pa.A[3] = srcc; pa.A[4] = trgc;
  for (int i = 0; i < 5; ++i) pa.W[i] = wT + (size_t)i * 524288;
  for (int i = 0; i < 5; ++i) pa.bias[i] = biasc + i * 512;
  pa.out[0] = q_s; pa.out[1] = s_key; pa.out[2] = t_key; pa.out[3] = sv_T; pa.out[4] = tv_T;
  hipLaunchKernelGGL(k_proj, dim3(768), dim3(256), 0, stream, pa);

  hipLaunchKernelGGL(k_scores, dim3(32, 2, 16), dim3(256), 0, stream, q_s, s_key, t_key, scores);
  hipLaunchKernelGGL(k_softmax, dim3(2048), dim3(256), 0, stream, scores);
  hipLaunchKernelGGL(k_ctx, dim3(32, 8, 4), dim3(256), 0, stream, scores, sv_T, tv_T, part);
  hipLaunchKernelGGL(k_out, dim3(8, 32, 1), dim3(256), 0, stream, qc, part, woT,
                     biasc + 5 * 512, d_out, query);
}

// Round 12
// 203.593 us; speedup vs baseline: 1.1155x; 1.0213x over previous
//
#include <hip/hip_runtime.h>
#include <cstdint>

// ---------- types & helpers ----------
typedef __attribute__((ext_vector_type(8))) short short8_t;
typedef __attribute__((ext_vector_type(8))) __bf16 bf16x8_t;
typedef __attribute__((ext_vector_type(4))) float f32x4_t;

__device__ __forceinline__ float bf2f(unsigned short u) {
  return __uint_as_float(((unsigned)u) << 16);
}
__device__ __forceinline__ unsigned short f2bf(float f) {  // RNE
  unsigned u = __float_as_uint(f);
  u += 0x7FFFu + ((u >> 16) & 1u);
  return (unsigned short)(u >> 16);
}

// MFMA wrapper: tolerate either builtin signature (short8 or bf16x8 operands).
template <typename V>
__device__ __forceinline__ auto mfma16_impl(V a, V b, f32x4_t c, int)
    -> decltype(__builtin_amdgcn_mfma_f32_16x16x32_bf16(a, b, c, 0, 0, 0)) {
  return __builtin_amdgcn_mfma_f32_16x16x32_bf16(a, b, c, 0, 0, 0);
}
template <typename V>
__device__ __forceinline__ f32x4_t mfma16_impl(V a, V b, f32x4_t c, long) {
  bf16x8_t ab = __builtin_bit_cast(bf16x8_t, a);
  bf16x8_t bb = __builtin_bit_cast(bf16x8_t, b);
  return __builtin_amdgcn_mfma_f32_16x16x32_bf16(ab, bb, c, 0, 0, 0);
}
__device__ __forceinline__ f32x4_t MFMA16(short8_t a, short8_t b, f32x4_t c) {
  return mfma16_impl(a, b, c, 0);
}

#define FRAG_VARS                                                       \
  const int tid = threadIdx.x;                                          \
  const int lane = tid & 63;                                            \
  const int wv = tid >> 6;                                              \
  const int mw = (wv >> 1) << 5;                                        \
  const int nw = (wv & 1) << 5;                                         \
  const int fr = lane & 15;                                             \
  const int fq = lane >> 4;                                             \
  f32x4_t acc00 = {0.f, 0.f, 0.f, 0.f};                                 \
  f32x4_t acc01 = acc00, acc10 = acc00, acc11 = acc00;

// Body sees: ml (local m), nl (local n), vv (float value). Variadic for commas.
#define GEMM_EPILOGUE(...)                                              \
  {                                                                     \
    const f32x4_t accs_[4] = {acc00, acc01, acc10, acc11};              \
    _Pragma("unroll") for (int im_ = 0; im_ < 2; ++im_)                 \
    _Pragma("unroll") for (int jn_ = 0; jn_ < 2; ++jn_) {               \
      f32x4_t aa_ = accs_[im_ * 2 + jn_];                               \
      const int ml0_ = mw + im_ * 16 + fq * 4;                          \
      const int nl = nw + jn_ * 16 + fr;                                \
      _Pragma("unroll") for (int r_ = 0; r_ < 4; ++r_) {                \
        const int ml = ml0_ + r_;                                       \
        const float vv = aa_[r_];                                       \
        __VA_ARGS__;                                                    \
      }                                                                 \
    }                                                                   \
  }

// ---------- async 16B/lane global->LDS (dest = wave-uniform base + lane*16) ----------
#if __has_builtin(__builtin_amdgcn_global_load_lds)
__device__ __forceinline__ void gload16(const void* g, void* lds_wave_base) {
  __builtin_amdgcn_global_load_lds(g, lds_wave_base, 16, 0, 0);
}
#else
__device__ __forceinline__ void gload16(const void* g, void* lds_wave_base) {
  const int lane = threadIdx.x & 63;  // synchronous fallback, same slot mapping
  ((uint4*)lds_wave_base)[lane] = *(const uint4*)g;
}
#endif

// ---------- inline dtype detector (per-block, deterministic, L2-broadcast) ----------
__device__ __forceinline__ int detect_f32(const void* q, int tid, int* sh) {
  const unsigned short* p = (const unsigned short*)q;
  int w = 0;
  for (int i = tid; i < 512; i += 256) {
    float v = bf2f(p[i]);
    float av = fabsf(v);
    if (!(av <= 1e4f) || (v != 0.f && av < 1e-10f)) ++w;  // NaN fails av<=1e4
  }
#pragma unroll
  for (int off = 32; off > 0; off >>= 1) w += __shfl_xor(w, off);
  if ((tid & 63) == 0) sh[tid >> 6] = w;
  __syncthreads();
  return (sh[0] + sh[1] + sh[2] + sh[3]) > 40;  // 1 = inputs are f32
}

// ---------- merged prep: convert (z<9) + weight transpose (z>=9), vectorized ----------
struct PrepArgs {
  const void* csrc[9];
  unsigned short* cdst[9];
  int cn[9];
  const void* tsrc[6];
  unsigned short* tdst[6];
  int tK[6];
};

__global__ __launch_bounds__(256) void k_prep(PrepArgs a) {
  __shared__ int shw[4];
  __shared__ unsigned short t[32][33];
  const int f32mode = detect_f32(a.csrc[0], threadIdx.x, shw);
  const int z = blockIdx.z;
  if (z < 9) {
    const int n = a.cn[z];  // all n divisible by 8
    const int bid = blockIdx.y * 16 + blockIdx.x;  // 0..767
    const int stride = 768 * 256;
    if (f32mode) {
      const float4* s4 = (const float4*)a.csrc[z];
      ushort4* d4 = (ushort4*)a.cdst[z];
      const int n4 = n >> 2;
      for (int i = bid * 256 + threadIdx.x; i < n4; i += stride) {
        float4 v = s4[i];
        ushort4 o;
        o.x = f2bf(v.x); o.y = f2bf(v.y); o.z = f2bf(v.z); o.w = f2bf(v.w);
        d4[i] = o;
      }
    } else {
      const uint4* s8 = (const uint4*)a.csrc[z];
      uint4* d8 = (uint4*)a.cdst[z];
      const int n8 = n >> 3;
      for (int i = bid * 256 + threadIdx.x; i < n8; i += stride) d8[i] = s8[i];
    }
  } else {
    const int w = z - 9;
    const int K = a.tK[w];
    const int k0 = blockIdx.y * 32, n0 = blockIdx.x * 32;
    if (k0 >= K) return;
    const int r = threadIdx.x >> 3;        // 0..31
    const int c4 = (threadIdx.x & 7) * 4;  // 0,4,..,28
    if (f32mode) {
      const float* s = (const float*)a.tsrc[w];
      float4 v = *(const float4*)&s[(size_t)(k0 + r) * 512 + n0 + c4];
      t[r][c4] = f2bf(v.x); t[r][c4 + 1] = f2bf(v.y);
      t[r][c4 + 2] = f2bf(v.z); t[r][c4 + 3] = f2bf(v.w);
    } else {
      const unsigned short* s = (const unsigned short*)a.tsrc[w];
      ushort4 v = *(const ushort4*)&s[(size_t)(k0 + r) * 512 + n0 + c4];
      t[r][c4] = v.x; t[r][c4 + 1] = v.y; t[r][c4 + 2] = v.z; t[r][c4 + 3] = v.w;
    }
    __syncthreads();
    unsigned short* d = a.tdst[w];
    ushort4 o;
    o.x = t[c4][r]; o.y = t[c4 + 1][r]; o.z = t[c4 + 2][r]; o.w = t[c4 + 3][r];
    *(ushort4*)&d[(size_t)(n0 + r) * K + k0 + c4] = o;
  }
}

// ---------- five projections: async global_load_lds, dbuf, XOR-swizzled LDS (R9 good) ----------
struct ProjArgs {
  const unsigned short* A[5];
  const unsigned short* W[5];
  const unsigned short* bias[5];
  unsigned short* out[5];
};

__global__ __launch_bounds__(256) void k_proj(ProjArgs args) {
  const int id = blockIdx.x;  // 0..767, all live
  int op, by, bx;
  if (id < 256) {
    op = 0; by = id >> 3; bx = id & 7;
  } else {
    int r2 = id - 256;
    op = 1 + (r2 >> 7); r2 &= 127; by = r2 >> 3; bx = r2 & 7;
  }
  const int m0 = by * 64, n0 = bx * 64;
  const unsigned short* A = args.A[op];
  const unsigned short* W = args.W[op];
  FRAG_VARS;
  __shared__ __align__(16) unsigned short sm[2][2][64 * 64];  // [buf][A=0/B=1] 32KB
  const int srow = lane >> 3;                       // 0..7 within wave's 8 rows
  const int scol = ((lane & 7) ^ srow) * 8;         // swizzled global elem offset
#pragma unroll
  for (int h = 0; h < 2; ++h) {
    const int row = h * 32 + wv * 8;
    gload16(&A[(size_t)(m0 + row + srow) * 1024 + scol], &sm[0][0][row * 64]);
    gload16(&W[(size_t)(n0 + row + srow) * 1024 + scol], &sm[0][1][row * 64]);
  }
  const int cs0 = ((fq) ^ (fr & 7)) * 8;        // ks=0 slot
  const int cs1 = ((4 + fq) ^ (fr & 7)) * 8;    // ks=1 slot
  for (int kc = 0; kc < 16; ++kc) {
    const int cur = kc & 1;
    __syncthreads();
    if (kc + 1 < 16) {
      const int nxt = cur ^ 1;
      const int k0 = (kc + 1) * 64;
#pragma unroll
      for (int h = 0; h < 2; ++h) {
        const int row = h * 32 + wv * 8;
        gload16(&A[(size_t)(m0 + row + srow) * 1024 + k0 + scol], &sm[nxt][0][row * 64]);
        gload16(&W[(size_t)(n0 + row + srow) * 1024 + k0 + scol], &sm[nxt][1][row * 64]);
      }
    }
    const unsigned short* Ab = sm[cur][0];
    const unsigned short* Bb = sm[cur][1];
    {
      short8_t a0 = *(const short8_t*)&Ab[(mw + fr) * 64 + cs0];
      short8_t a1 = *(const short8_t*)&Ab[(mw + 16 + fr) * 64 + cs0];
      short8_t b0 = *(const short8_t*)&Bb[(nw + fr) * 64 + cs0];
      short8_t b1 = *(const short8_t*)&Bb[(nw + 16 + fr) * 64 + cs0];
      acc00 = MFMA16(a0, b0, acc00);
      acc01 = MFMA16(a0, b1, acc01);
      acc10 = MFMA16(a1, b0, acc10);
      acc11 = MFMA16(a1, b1, acc11);
    }
    {
      short8_t a0 = *(const short8_t*)&Ab[(mw + fr) * 64 + cs1];
      short8_t a1 = *(const short8_t*)&Ab[(mw + 16 + fr) * 64 + cs1];
      short8_t b0 = *(const short8_t*)&Bb[(nw + fr) * 64 + cs1];
      short8_t b1 = *(const short8_t*)&Bb[(nw + 16 + fr) * 64 + cs1];
      acc00 = MFMA16(a0, b0, acc00);
      acc01 = MFMA16(a0, b1, acc01);
      acc10 = MFMA16(a1, b0, acc10);
      acc11 = MFMA16(a1, b1, acc11);
    }
  }
  const float scale = (op == 0) ? 0.044194173824159216f : 1.0f;
  const unsigned short* bias = args.bias[op];
  unsigned short* out = args.out[op];
  GEMM_EPILOGUE({
    const float v = (vv + bf2f(bias[n0 + nl])) * scale;
    const int m = m0 + ml;
    const int n = n0 + nl;
    if (op < 3) {
      out[(size_t)m * 512 + n] = f2bf(v);
    } else {
      const int bb = m >> 6;
      const int ss = m & 63;
      out[(size_t)bb * 32768 + (size_t)n * 64 + ss] = f2bf(v);
    }
  });
}

// ---------- scores: async dbuf staging, 64-k chunks (R10 known-good) ----------
__global__ __launch_bounds__(256) void k_scores(
    const unsigned short* __restrict__ qs, const unsigned short* __restrict__ skey,
    const unsigned short* __restrict__ tkey, unsigned short* __restrict__ scores) {
  const int b = blockIdx.z;
  const int m0 = blockIdx.y * 64;
  const int sx = blockIdx.x;  // s = sx*2 + {0,1}
  const int tid = threadIdx.x;
  const int lane = tid & 63;
  const int wv = tid >> 6;
  const int mw = (wv >> 1) << 5;
  const int nw = (wv & 1) << 5;
  const int fr = lane & 15;
  const int fq = lane >> 4;
  __shared__ __align__(16) unsigned short qS[2][64 * 64];   // 16KB
  __shared__ __align__(16) unsigned short tkS[2][64 * 64];  // 16KB
  __shared__ __align__(16) unsigned short skL[1024];        // 2KB: 2 s-rows x 512
  f32x4_t acc[2][4];
#pragma unroll
  for (int s = 0; s < 2; ++s)
#pragma unroll
    for (int i = 0; i < 4; ++i) acc[s][i] = (f32x4_t){0.f, 0.f, 0.f, 0.f};
  const unsigned short* qb = qs + ((size_t)b * 128 + m0) * 512;
  const unsigned short* tkb = tkey + (size_t)b * 64 * 512;
  const unsigned short* skb = skey + ((size_t)b * 64 + sx * 2) * 512;
  if (tid < 128) *(uint4*)&skL[tid * 8] = *(const uint4*)&skb[tid * 8];
  const int srow = lane >> 3;
  const int scol = ((lane & 7) ^ srow) * 8;
#pragma unroll
  for (int h = 0; h < 2; ++h) {
    const int row = h * 32 + wv * 8;
    gload16(&qb[(size_t)(row + srow) * 512 + scol], &qS[0][row * 64]);
    gload16(&tkb[(size_t)(row + srow) * 512 + scol], &tkS[0][row * 64]);
  }
  const int cs0 = ((fq) ^ (fr & 7)) * 8;
  const int cs1 = ((4 + fq) ^ (fr & 7)) * 8;
  for (int kc = 0; kc < 8; ++kc) {
    const int cur = kc & 1;
    __syncthreads();  // drains prev prefetch (overlapped with prev compute)
    if (kc + 1 < 8) {
      const int k0 = (kc + 1) * 64;
      const int nxt = cur ^ 1;
#pragma unroll
      for (int h = 0; h < 2; ++h) {
        const int row = h * 32 + wv * 8;
        gload16(&qb[(size_t)(row + srow) * 512 + k0 + scol], &qS[nxt][row * 64]);
        gload16(&tkb[(size_t)(row + srow) * 512 + k0 + scol], &tkS[nxt][row * 64]);
      }
    }
#pragma unroll
    for (int ks = 0; ks < 2; ++ks) {
      const int cs = ks ? cs1 : cs0;
      short8_t a0 = *(const short8_t*)&qS[cur][(mw + fr) * 64 + cs];
      short8_t a1 = *(const short8_t*)&qS[cur][(mw + 16 + fr) * 64 + cs];
      uint4 tq[2];
      tq[0] = *(const uint4*)&tkS[cur][(nw + fr) * 64 + cs];
      tq[1] = *(const uint4*)&tkS[cur][(nw + 16 + fr) * 64 + cs];
      float tlo[2][4], thi[2][4];
#pragma unroll
      for (int h = 0; h < 2; ++h) {
        const unsigned* tw = (const unsigned*)&tq[h];
#pragma unroll
        for (int j = 0; j < 4; ++j) {
          tlo[h][j] = __uint_as_float(tw[j] << 16);
          thi[h][j] = __uint_as_float(tw[j] & 0xffff0000u);
        }
      }
      const int koff = kc * 64 + ks * 32 + fq * 8;  // logical k for sk (broadcast)
#pragma unroll
      for (int s = 0; s < 2; ++s) {
        uint4 skq = *(const uint4*)&skL[s * 512 + koff];
        const unsigned* sw = (const unsigned*)&skq;
        union { short8_t v; unsigned w[4]; } b0, b1;
#pragma unroll
        for (int j = 0; j < 4; ++j) {
          const float slo = __uint_as_float(sw[j] << 16);
          const float shi = __uint_as_float(sw[j] & 0xffff0000u);
          b0.w[j] = __builtin_amdgcn_perm(__float_as_uint(thi[0][j] * shi),
                                          __float_as_uint(tlo[0][j] * slo), 0x07060302);
          b1.w[j] = __builtin_amdgcn_perm(__float_as_uint(thi[1][j] * shi),
                                          __float_as_uint(tlo[1][j] * slo), 0x07060302);
        }
        acc[s][0] = MFMA16(a0, b0.v, acc[s][0]);
        acc[s][1] = MFMA16(a0, b1.v, acc[s][1]);
        acc[s][2] = MFMA16(a1, b0.v, acc[s][2]);
        acc[s][3] = MFMA16(a1, b1.v, acc[s][3]);
      }
    }
  }
#pragma unroll
  for (int s = 0; s < 2; ++s) {
    unsigned short* out = scores + ((size_t)b * 128 + m0) * 4096 + (size_t)(sx * 2 + s) * 64;
#pragma unroll
    for (int im = 0; im < 2; ++im)
#pragma unroll
      for (int jn = 0; jn < 2; ++jn) {
        f32x4_t aa = acc[s][im * 2 + jn];
        const int col = nw + jn * 16 + fr;
#pragma unroll
        for (int r = 0; r < 4; ++r) {
          const int row = mw + im * 16 + fq * 4 + r;
          out[(size_t)row * 4096 + col] = f2bf(aa[r]);
        }
      }
  }
}

// ---------- in-place softmax over each row of 4096 ----------
__global__ __launch_bounds__(256) void k_softmax(unsigned short* __restrict__ s) {
  unsigned short* p = s + (size_t)blockIdx.x * 4096;
  const int t = threadIdx.x;
  union U8 { uint4 q; unsigned short u[8]; };
  U8 a, b;
  a.q = *(const uint4*)&p[t * 16];
  b.q = *(const uint4*)&p[t * 16 + 8];
  float x[16];
#pragma unroll
  for (int j = 0; j < 8; ++j) { x[j] = bf2f(a.u[j]); x[8 + j] = bf2f(b.u[j]); }
  float m = x[0];
#pragma unroll
  for (int j = 1; j < 16; ++j) m = fmaxf(m, x[j]);
  for (int off = 32; off > 0; off >>= 1) m = fmaxf(m, __shfl_xor(m, off));
  __shared__ float redm[4], reds[4];
  if ((t & 63) == 0) redm[t >> 6] = m;
  __syncthreads();
  m = fmaxf(fmaxf(redm[0], redm[1]), fmaxf(redm[2], redm[3]));
  float sum = 0.f;
#pragma unroll
  for (int j = 0; j < 16; ++j) { x[j] = __expf(x[j] - m); sum += x[j]; }
  for (int off = 32; off > 0; off >>= 1) sum += __shfl_xor(sum, off);
  if ((t & 63) == 0) reds[t >> 6] = sum;
  __syncthreads();
  sum = reds[0] + reds[1] + reds[2] + reds[3];
  const float inv = 1.0f / sum;
#pragma unroll
  for (int j = 0; j < 8; ++j) {
    a.u[j] = f2bf(x[j] * inv);
    b.u[j] = f2bf(x[8 + j] * inv);
  }
  *(uint4*)&p[t * 16] = a.q;
  *(uint4*)&p[t * 16 + 8] = b.q;
}

// ---------- ctx partials: s-factored, no repack (R11 known-good) ----------
__global__ __launch_bounds__(256) void k_ctx(
    const unsigned short* __restrict__ p, const unsigned short* __restrict__ svT,
    const unsigned short* __restrict__ tvT, unsigned short* __restrict__ part) {
  const int b = blockIdx.x >> 1;
  const int m0 = (blockIdx.x & 1) * 64;
  const int n0 = blockIdx.y * 64;
  const int z = blockIdx.z;  // s-chunk: s in [z*16, z*16+16)
  FRAG_VARS;
  __shared__ __align__(16) unsigned short tvl[64 * 72];
  __shared__ __align__(16) unsigned short svl[64 * 24];
  {
    const unsigned short* tvb = tvT + (size_t)b * 32768 + (size_t)n0 * 64;
    const unsigned short* svb = svT + (size_t)b * 32768 + (size_t)n0 * 64 + z * 16;
#pragma unroll
    for (int it = 0; it < 2; ++it) {
      const int idx = tid + it * 256;
      const int r = idx >> 3, c = (idx & 7) * 8;
      *(uint4*)&tvl[r * 72 + c] = *(const uint4*)&tvb[(size_t)r * 64 + c];
    }
    if (tid < 128) {
      const int r = tid >> 1, c = (tid & 1) * 8;
      *(uint4*)&svl[r * 24 + c] = *(const uint4*)&svb[(size_t)r * 64 + c];
    }
  }
  __syncthreads();
  short8_t bv[2][2];
  bv[0][0] = *(const short8_t*)&tvl[(nw + fr) * 72 + fq * 8];
  bv[0][1] = *(const short8_t*)&tvl[(nw + fr) * 72 + 32 + fq * 8];
  bv[1][0] = *(const short8_t*)&tvl[(nw + 16 + fr) * 72 + fq * 8];
  bv[1][1] = *(const short8_t*)&tvl[(nw + 16 + fr) * 72 + 32 + fq * 8];
  const unsigned short* ar0 =
      p + ((size_t)b * 128 + m0 + mw + fr) * 4096 + z * 1024 + fq * 8;
  const unsigned short* ar1 = ar0 + (size_t)16 * 4096;
  uint4 pa[2][2][2];
#pragma unroll
  for (int d = 0; d < 2; ++d) {
    pa[d][0][0] = *(const uint4*)(ar0 + d * 64);
    pa[d][0][1] = *(const uint4*)(ar0 + d * 64 + 32);
    pa[d][1][0] = *(const uint4*)(ar1 + d * 64);
    pa[d][1][1] = *(const uint4*)(ar1 + d * 64 + 32);
  }
#pragma unroll 2
  for (int s = 0; s < 16; ++s) {
    const int sl = s & 1;
    short8_t a00 = __builtin_bit_cast(short8_t, pa[sl][0][0]);
    short8_t a01 = __builtin_bit_cast(short8_t, pa[sl][0][1]);
    short8_t a10 = __builtin_bit_cast(short8_t, pa[sl][1][0]);
    short8_t a11 = __builtin_bit_cast(short8_t, pa[sl][1][1]);
    if (s + 2 < 16) {
      const int off = (s + 2) * 64;
      pa[sl][0][0] = *(const uint4*)(ar0 + off);
      pa[sl][0][1] = *(const uint4*)(ar0 + off + 32);
      pa[sl][1][0] = *(const uint4*)(ar1 + off);
      pa[sl][1][1] = *(const uint4*)(ar1 + off + 32);
    }
    const f32x4_t z4 = {0.f, 0.f, 0.f, 0.f};
    f32x4_t M00 = MFMA16(a00, bv[0][0], z4);
    M00 = MFMA16(a01, bv[0][1], M00);
    f32x4_t M01 = MFMA16(a00, bv[1][0], z4);
    M01 = MFMA16(a01, bv[1][1], M01);
    f32x4_t M10 = MFMA16(a10, bv[0][0], z4);
    M10 = MFMA16(a11, bv[0][1], M10);
    f32x4_t M11 = MFMA16(a10, bv[1][0], z4);
    M11 = MFMA16(a11, bv[1][1], M11);
    const float sv0 = bf2f(svl[(nw + fr) * 24 + s]);
    const float sv1 = bf2f(svl[(nw + 16 + fr) * 24 + s]);
#pragma unroll
    for (int r = 0; r < 4; ++r) {
      acc00[r] += sv0 * M00[r];
      acc01[r] += sv1 * M01[r];
      acc10[r] += sv0 * M10[r];
      acc11[r] += sv1 * M11[r];
    }
  }
  unsigned short* out = part + ((size_t)z * 2048 + (size_t)b * 128 + m0) * 512 + n0;
  GEMM_EPILOGUE({ out[(size_t)ml * 512 + nl] = f2bf(vv); });
}

// ---------- reduce 4 bf16 partials -> bf16 ctx ----------
__global__ __launch_bounds__(256) void k_reduce(const unsigned short* __restrict__ part,
                                                unsigned short* __restrict__ ctx) {
  const size_t N = (size_t)2048 * 512;
  const size_t i = ((size_t)blockIdx.x * 256 + threadIdx.x) * 8;
  float s[8];
#pragma unroll
  for (int j = 0; j < 8; ++j) s[j] = 0.f;
#pragma unroll
  for (int z = 0; z < 4; ++z) {
    union { uint4 q; unsigned short u[8]; } t;
    t.q = *(const uint4*)&part[z * N + i];
#pragma unroll
    for (int j = 0; j < 8; ++j) s[j] += bf2f(t.u[j]);
  }
  union { uint4 q; unsigned short u[8]; } o;
#pragma unroll
  for (int j = 0; j < 8; ++j) o.u[j] = f2bf(s[j]);
  *(uint4*)&ctx[i] = o.q;
}

// ---------- out = relu(concat(query, ctx) @ Wo + bo): async dbuf, 24 chunks ----------
__global__ __launch_bounds__(256) void k_out(
    const unsigned short* __restrict__ query, const unsigned short* __restrict__ ctx,
    const unsigned short* __restrict__ WoT, const unsigned short* __restrict__ bo,
    void* __restrict__ outv, const void* __restrict__ rawq) {
  __shared__ int shw[4];
  const int f32mode = detect_f32(rawq, threadIdx.x, shw);
  const int m0 = blockIdx.y * 64, n0 = blockIdx.x * 64;
  FRAG_VARS;
  __shared__ __align__(16) unsigned short sm[2][2][64 * 64];  // [buf][A/B] 32KB
  const int srow = lane >> 3;
  const int scol = ((lane & 7) ^ srow) * 8;
  // A source for chunk kc: qc rows (stride 1024) for kc<16, ctx rows (stride 512) after.
  auto a_src = [&](int kc, int row) -> const unsigned short* {
    if (kc < 16) return &query[(size_t)(m0 + row + srow) * 1024 + kc * 64 + scol];
    return &ctx[(size_t)(m0 + row + srow) * 512 + (kc - 16) * 64 + scol];
  };
#pragma unroll
  for (int h = 0; h < 2; ++h) {
    const int row = h * 32 + wv * 8;
    gload16(a_src(0, row), &sm[0][0][row * 64]);
    gload16(&WoT[(size_t)(n0 + row + srow) * 1536 + scol], &sm[0][1][row * 64]);
  }
  const int cs0 = ((fq) ^ (fr & 7)) * 8;
  const int cs1 = ((4 + fq) ^ (fr & 7)) * 8;
  for (int kc = 0; kc < 24; ++kc) {
    const int cur = kc & 1;
    __syncthreads();
    if (kc + 1 < 24) {
      const int nxt = cur ^ 1;
      const int k0 = (kc + 1) * 64;
#pragma unroll
      for (int h = 0; h < 2; ++h) {
        const int row = h * 32 + wv * 8;
        gload16(a_src(kc + 1, row), &sm[nxt][0][row * 64]);
        gload16(&WoT[(size_t)(n0 + row + srow) * 1536 + k0 + scol], &sm[nxt][1][row * 64]);
      }
    }
    const unsigned short* Ab = sm[cur][0];
    const unsigned short* Bb = sm[cur][1];
    {
      short8_t a0 = *(const short8_t*)&Ab[(mw + fr) * 64 + cs0];
      short8_t a1 = *(const short8_t*)&Ab[(mw + 16 + fr) * 64 + cs0];
      short8_t b0 = *(const short8_t*)&Bb[(nw + fr) * 64 + cs0];
      short8_t b1 = *(const short8_t*)&Bb[(nw + 16 + fr) * 64 + cs0];
      acc00 = MFMA16(a0, b0, acc00);
      acc01 = MFMA16(a0, b1, acc01);
      acc10 = MFMA16(a1, b0, acc10);
      acc11 = MFMA16(a1, b1, acc11);
    }
    {
      short8_t a0 = *(const short8_t*)&Ab[(mw + fr) * 64 + cs1];
      short8_t a1 = *(const short8_t*)&Ab[(mw + 16 + fr) * 64 + cs1];
      short8_t b0 = *(const short8_t*)&Bb[(nw + fr) * 64 + cs1];
      short8_t b1 = *(const short8_t*)&Bb[(nw + 16 + fr) * 64 + cs1];
      acc00 = MFMA16(a0, b0, acc00);
      acc01 = MFMA16(a0, b1, acc01);
      acc10 = MFMA16(a1, b0, acc10);
      acc11 = MFMA16(a1, b1, acc11);
    }
  }
  GEMM_EPILOGUE({
    float v = fmaxf(vv + bf2f(bo[n0 + nl]), 0.f);
    const size_t idx = (size_t)(m0 + ml) * 512 + n0 + nl;
    if (f32mode)
      ((float*)outv)[idx] = v;
    else
      ((unsigned short*)outv)[idx] = f2bf(v);
  });
}

// ---------- launch ----------
extern "C" void kernel_launch(void* const* d_in, const int* in_sizes, int n_in,
                              void* d_out, int out_size, void* d_ws, size_t ws_size,
                              hipStream_t stream) {
  const void* query = d_in[0];
  const void* src = d_in[1];
  const void* trg = d_in[2];
  const void* Wq = d_in[3];
  const void* bq = d_in[4];
  const void* Ws = d_in[5];
  const void* bs = d_in[6];
  const void* Wt = d_in[7];
  const void* bt = d_in[8];
  const void* Wsv = d_in[9];
  const void* bsv = d_in[10];
  const void* Wtv = d_in[11];
  const void* btv = d_in[12];
  const void* Wo = d_in[13];
  const void* bo = d_in[14];

  char* ws = (char*)d_ws;
  size_t off = 0;
  auto alloc = [&](size_t bytes) {
    char* ptr = ws + off;
    off = (off + bytes + 255) & ~(size_t)255;
    return ptr;
  };
  unsigned short* qc = (unsigned short*)alloc((size_t)2048 * 1024 * 2);
  unsigned short* srcc = (unsigned short*)alloc((size_t)1024 * 1024 * 2);
  unsigned short* trgc = (unsigned short*)alloc((size_t)1024 * 1024 * 2);
  unsigned short* biasc = (unsigned short*)alloc((size_t)6 * 512 * 2);
  unsigned short* wT = (unsigned short*)alloc((size_t)5 * 524288 * 2);
  unsigned short* woT = (unsigned short*)alloc((size_t)512 * 1536 * 2);
  unsigned short* q_s = (unsigned short*)alloc((size_t)2048 * 512 * 2);
  unsigned short* s_key = (unsigned short*)alloc((size_t)1024 * 512 * 2);
  unsigned short* t_key = (unsigned short*)alloc((size_t)1024 * 512 * 2);
  unsigned short* sv_T = (unsigned short*)alloc((size_t)16 * 512 * 64 * 2);
  unsigned short* tv_T = (unsigned short*)alloc((size_t)16 * 512 * 64 * 2);
  unsigned short* scores = (unsigned short*)alloc((size_t)2048 * 4096 * 2);
  unsigned short* part = (unsigned short*)alloc((size_t)4 * 2048 * 512 * 2);
  unsigned short* ctx = (unsigned short*)alloc((size_t)2048 * 512 * 2);
  (void)ws_size; (void)in_sizes; (void)n_in; (void)out_size;

  PrepArgs pr;
  pr.csrc[0] = query; pr.csrc[1] = src; pr.csrc[2] = trg;
  pr.csrc[3] = bq; pr.csrc[4] = bs; pr.csrc[5] = bt;
  pr.csrc[6] = bsv; pr.csrc[7] = btv; pr.csrc[8] = bo;
  pr.cdst[0] = qc; pr.cdst[1] = srcc; pr.cdst[2] = trgc;
  for (int i = 0; i < 6; ++i) pr.cdst[3 + i] = biasc + i * 512;
  pr.cn[0] = 2048 * 1024; pr.cn[1] = 1024 * 1024; pr.cn[2] = 1024 * 1024;
  for (int i = 0; i < 6; ++i) pr.cn[3 + i] = 512;
  pr.tsrc[0] = Wq; pr.tsrc[1] = Ws; pr.tsrc[2] = Wt;
  pr.tsrc[3] = Wsv; pr.tsrc[4] = Wtv; pr.tsrc[5] = Wo;
  for (int i = 0; i < 5; ++i) { pr.tdst[i] = wT + (size_t)i * 524288; pr.tK[i] = 1024; }
  pr.tdst[5] = woT; pr.tK[5] = 1536;
  hipLaunchKernelGGL(k_prep, dim3(16, 48, 15), dim3(256), 0, stream, pr);

  ProjArgs pa;
  pa.A[0] = qc; pa.A[1] = srcc; pa.A[2] = trgc; pa.A[3] = srcc; pa.A[4] = trgc;
  for (int i = 0; i < 5; ++i) pa.W[i] = wT + (size_t)i * 524288;
  for (int i = 0; i < 5; ++i) pa.bias[i] = biasc + i * 512;
  pa.out[0] = q_s; pa.out[1] = s_key; pa.out[2] = t_key; pa.out[3] = sv_T; pa.out[4] = tv_T;
  hipLaunchKernelGGL(k_proj, dim3(768), dim3(256), 0, stream, pa);

  hipLaunchKernelGGL(k_scores, dim3(32, 2, 16), dim3(256), 0, stream, q_s, s_key, t_key, scores);
  hipLaunchKernelGGL(k_softmax, dim3(2048), dim3(256), 0, stream, scores);
  hipLaunchKernelGGL(k_ctx, dim3(32, 8, 4), dim3(256), 0, stream, scores, sv_T, tv_T, part);
  hipLaunchKernelGGL(k_reduce, dim3(512), dim3(256), 0, stream, part, ctx);
  hipLaunchKernelGGL(k_out, dim3(8, 32, 1), dim3(256), 0, stream, qc, ctx, woT,
                     biasc + 5 * 512, d_out, query);
}

// Round 13
// 199.702 us; speedup vs baseline: 1.1373x; 1.0195x over previous
//
#include <hip/hip_runtime.h>
#include <cstdint>

// ---------- types & helpers ----------
typedef __attribute__((ext_vector_type(8))) short short8_t;
typedef __attribute__((ext_vector_type(8))) __bf16 bf16x8_t;
typedef __attribute__((ext_vector_type(4))) float f32x4_t;

__device__ __forceinline__ float bf2f(unsigned short u) {
  return __uint_as_float(((unsigned)u) << 16);
}
__device__ __forceinline__ unsigned short f2bf(float f) {  // RNE
  unsigned u = __float_as_uint(f);
  u += 0x7FFFu + ((u >> 16) & 1u);
  return (unsigned short)(u >> 16);
}

// MFMA wrapper: tolerate either builtin signature (short8 or bf16x8 operands).
template <typename V>
__device__ __forceinline__ auto mfma16_impl(V a, V b, f32x4_t c, int)
    -> decltype(__builtin_amdgcn_mfma_f32_16x16x32_bf16(a, b, c, 0, 0, 0)) {
  return __builtin_amdgcn_mfma_f32_16x16x32_bf16(a, b, c, 0, 0, 0);
}
template <typename V>
__device__ __forceinline__ f32x4_t mfma16_impl(V a, V b, f32x4_t c, long) {
  bf16x8_t ab = __builtin_bit_cast(bf16x8_t, a);
  bf16x8_t bb = __builtin_bit_cast(bf16x8_t, b);
  return __builtin_amdgcn_mfma_f32_16x16x32_bf16(ab, bb, c, 0, 0, 0);
}
__device__ __forceinline__ f32x4_t MFMA16(short8_t a, short8_t b, f32x4_t c) {
  return mfma16_impl(a, b, c, 0);
}

#define FRAG_VARS                                                       \
  const int tid = threadIdx.x;                                          \
  const int lane = tid & 63;                                            \
  const int wv = tid >> 6;                                              \
  const int mw = (wv >> 1) << 5;                                        \
  const int nw = (wv & 1) << 5;                                         \
  const int fr = lane & 15;                                             \
  const int fq = lane >> 4;                                             \
  f32x4_t acc00 = {0.f, 0.f, 0.f, 0.f};                                 \
  f32x4_t acc01 = acc00, acc10 = acc00, acc11 = acc00;

// Body sees: ml (local m), nl (local n), vv (float value). Variadic for commas.
#define GEMM_EPILOGUE(...)                                              \
  {                                                                     \
    const f32x4_t accs_[4] = {acc00, acc01, acc10, acc11};              \
    _Pragma("unroll") for (int im_ = 0; im_ < 2; ++im_)                 \
    _Pragma("unroll") for (int jn_ = 0; jn_ < 2; ++jn_) {               \
      f32x4_t aa_ = accs_[im_ * 2 + jn_];                               \
      const int ml0_ = mw + im_ * 16 + fq * 4;                          \
      const int nl = nw + jn_ * 16 + fr;                                \
      _Pragma("unroll") for (int r_ = 0; r_ < 4; ++r_) {                \
        const int ml = ml0_ + r_;                                       \
        const float vv = aa_[r_];                                       \
        __VA_ARGS__;                                                    \
      }                                                                 \
    }                                                                   \
  }

// ---------- async 16B/lane global->LDS (dest = wave-uniform base + lane*16) ----------
#if __has_builtin(__builtin_amdgcn_global_load_lds)
__device__ __forceinline__ void gload16(const void* g, void* lds_wave_base) {
  __builtin_amdgcn_global_load_lds(g, lds_wave_base, 16, 0, 0);
}
#else
__device__ __forceinline__ void gload16(const void* g, void* lds_wave_base) {
  const int lane = threadIdx.x & 63;  // synchronous fallback, same slot mapping
  ((uint4*)lds_wave_base)[lane] = *(const uint4*)g;
}
#endif

// ---------- inline dtype detector (per-block, deterministic, L2-broadcast) ----------
__device__ __forceinline__ int detect_f32(const void* q, int tid, int* sh) {
  const unsigned short* p = (const unsigned short*)q;
  int w = 0;
  for (int i = tid; i < 512; i += 256) {
    float v = bf2f(p[i]);
    float av = fabsf(v);
    if (!(av <= 1e4f) || (v != 0.f && av < 1e-10f)) ++w;  // NaN fails av<=1e4
  }
#pragma unroll
  for (int off = 32; off > 0; off >>= 1) w += __shfl_xor(w, off);
  if ((tid & 63) == 0) sh[tid >> 6] = w;
  __syncthreads();
  return (sh[0] + sh[1] + sh[2] + sh[3]) > 40;  // 1 = inputs are f32
}

// ---------- merged prep: convert (z<9) + weight transpose (z>=9), vectorized ----------
struct PrepArgs {
  const void* csrc[9];
  unsigned short* cdst[9];
  int cn[9];
  const void* tsrc[6];
  unsigned short* tdst[6];
  int tK[6];
};

__global__ __launch_bounds__(256) void k_prep(PrepArgs a) {
  __shared__ int shw[4];
  __shared__ unsigned short t[32][33];
  const int f32mode = detect_f32(a.csrc[0], threadIdx.x, shw);
  const int z = blockIdx.z;
  if (z < 9) {
    const int n = a.cn[z];  // all n divisible by 8
    const int bid = blockIdx.y * 16 + blockIdx.x;  // 0..767
    const int stride = 768 * 256;
    if (f32mode) {
      const float4* s4 = (const float4*)a.csrc[z];
      ushort4* d4 = (ushort4*)a.cdst[z];
      const int n4 = n >> 2;
      for (int i = bid * 256 + threadIdx.x; i < n4; i += stride) {
        float4 v = s4[i];
        ushort4 o;
        o.x = f2bf(v.x); o.y = f2bf(v.y); o.z = f2bf(v.z); o.w = f2bf(v.w);
        d4[i] = o;
      }
    } else {
      const uint4* s8 = (const uint4*)a.csrc[z];
      uint4* d8 = (uint4*)a.cdst[z];
      const int n8 = n >> 3;
      for (int i = bid * 256 + threadIdx.x; i < n8; i += stride) d8[i] = s8[i];
    }
  } else {
    const int w = z - 9;
    const int K = a.tK[w];
    const int k0 = blockIdx.y * 32, n0 = blockIdx.x * 32;
    if (k0 >= K) return;
    const int r = threadIdx.x >> 3;        // 0..31
    const int c4 = (threadIdx.x & 7) * 4;  // 0,4,..,28
    if (f32mode) {
      const float* s = (const float*)a.tsrc[w];
      float4 v = *(const float4*)&s[(size_t)(k0 + r) * 512 + n0 + c4];
      t[r][c4] = f2bf(v.x); t[r][c4 + 1] = f2bf(v.y);
      t[r][c4 + 2] = f2bf(v.z); t[r][c4 + 3] = f2bf(v.w);
    } else {
      const unsigned short* s = (const unsigned short*)a.tsrc[w];
      ushort4 v = *(const ushort4*)&s[(size_t)(k0 + r) * 512 + n0 + c4];
      t[r][c4] = v.x; t[r][c4 + 1] = v.y; t[r][c4 + 2] = v.z; t[r][c4 + 3] = v.w;
    }
    __syncthreads();
    unsigned short* d = a.tdst[w];
    ushort4 o;
    o.x = t[c4][r]; o.y = t[c4 + 1][r]; o.z = t[c4 + 2][r]; o.w = t[c4 + 3][r];
    *(ushort4*)&d[(size_t)(n0 + r) * K + k0 + c4] = o;
  }
}

// ---------- five projections: async global_load_lds, dbuf, XOR-swizzled LDS (R9 good) ----------
struct ProjArgs {
  const unsigned short* A[5];
  const unsigned short* W[5];
  const unsigned short* bias[5];
  unsigned short* out[5];
};

__global__ __launch_bounds__(256) void k_proj(ProjArgs args) {
  const int id = blockIdx.x;  // 0..767, all live
  int op, by, bx;
  if (id < 256) {
    op = 0; by = id >> 3; bx = id & 7;
  } else {
    int r2 = id - 256;
    op = 1 + (r2 >> 7); r2 &= 127; by = r2 >> 3; bx = r2 & 7;
  }
  const int m0 = by * 64, n0 = bx * 64;
  const unsigned short* A = args.A[op];
  const unsigned short* W = args.W[op];
  FRAG_VARS;
  __shared__ __align__(16) unsigned short sm[2][2][64 * 64];  // [buf][A=0/B=1] 32KB
  const int srow = lane >> 3;                       // 0..7 within wave's 8 rows
  const int scol = ((lane & 7) ^ srow) * 8;         // swizzled global elem offset
#pragma unroll
  for (int h = 0; h < 2; ++h) {
    const int row = h * 32 + wv * 8;
    gload16(&A[(size_t)(m0 + row + srow) * 1024 + scol], &sm[0][0][row * 64]);
    gload16(&W[(size_t)(n0 + row + srow) * 1024 + scol], &sm[0][1][row * 64]);
  }
  const int cs0 = ((fq) ^ (fr & 7)) * 8;        // ks=0 slot
  const int cs1 = ((4 + fq) ^ (fr & 7)) * 8;    // ks=1 slot
  for (int kc = 0; kc < 16; ++kc) {
    const int cur = kc & 1;
    __syncthreads();
    if (kc + 1 < 16) {
      const int nxt = cur ^ 1;
      const int k0 = (kc + 1) * 64;
#pragma unroll
      for (int h = 0; h < 2; ++h) {
        const int row = h * 32 + wv * 8;
        gload16(&A[(size_t)(m0 + row + srow) * 1024 + k0 + scol], &sm[nxt][0][row * 64]);
        gload16(&W[(size_t)(n0 + row + srow) * 1024 + k0 + scol], &sm[nxt][1][row * 64]);
      }
    }
    const unsigned short* Ab = sm[cur][0];
    const unsigned short* Bb = sm[cur][1];
    {
      short8_t a0 = *(const short8_t*)&Ab[(mw + fr) * 64 + cs0];
      short8_t a1 = *(const short8_t*)&Ab[(mw + 16 + fr) * 64 + cs0];
      short8_t b0 = *(const short8_t*)&Bb[(nw + fr) * 64 + cs0];
      short8_t b1 = *(const short8_t*)&Bb[(nw + 16 + fr) * 64 + cs0];
      acc00 = MFMA16(a0, b0, acc00);
      acc01 = MFMA16(a0, b1, acc01);
      acc10 = MFMA16(a1, b0, acc10);
      acc11 = MFMA16(a1, b1, acc11);
    }
    {
      short8_t a0 = *(const short8_t*)&Ab[(mw + fr) * 64 + cs1];
      short8_t a1 = *(const short8_t*)&Ab[(mw + 16 + fr) * 64 + cs1];
      short8_t b0 = *(const short8_t*)&Bb[(nw + fr) * 64 + cs1];
      short8_t b1 = *(const short8_t*)&Bb[(nw + 16 + fr) * 64 + cs1];
      acc00 = MFMA16(a0, b0, acc00);
      acc01 = MFMA16(a0, b1, acc01);
      acc10 = MFMA16(a1, b0, acc10);
      acc11 = MFMA16(a1, b1, acc11);
    }
  }
  const float scale = (op == 0) ? 0.044194173824159216f : 1.0f;
  const unsigned short* bias = args.bias[op];
  unsigned short* out = args.out[op];
  GEMM_EPILOGUE({
    const float v = (vv + bf2f(bias[n0 + nl])) * scale;
    const int m = m0 + ml;
    const int n = n0 + nl;
    if (op < 3) {
      out[(size_t)m * 512 + n] = f2bf(v);
    } else {
      const int bb = m >> 6;
      const int ss = m & 63;
      out[(size_t)bb * 32768 + (size_t)n * 64 + ss] = f2bf(v);
    }
  });
}

// ---------- scores: async dbuf staging, 64-k chunks (R10 known-good) ----------
__global__ __launch_bounds__(256) void k_scores(
    const unsigned short* __restrict__ qs, const unsigned short* __restrict__ skey,
    const unsigned short* __restrict__ tkey, unsigned short* __restrict__ scores) {
  const int b = blockIdx.z;
  const int m0 = blockIdx.y * 64;
  const int sx = blockIdx.x;  // s = sx*2 + {0,1}
  const int tid = threadIdx.x;
  const int lane = tid & 63;
  const int wv = tid >> 6;
  const int mw = (wv >> 1) << 5;
  const int nw = (wv & 1) << 5;
  const int fr = lane & 15;
  const int fq = lane >> 4;
  __shared__ __align__(16) unsigned short qS[2][64 * 64];   // 16KB
  __shared__ __align__(16) unsigned short tkS[2][64 * 64];  // 16KB
  __shared__ __align__(16) unsigned short skL[1024];        // 2KB: 2 s-rows x 512
  f32x4_t acc[2][4];
#pragma unroll
  for (int s = 0; s < 2; ++s)
#pragma unroll
    for (int i = 0; i < 4; ++i) acc[s][i] = (f32x4_t){0.f, 0.f, 0.f, 0.f};
  const unsigned short* qb = qs + ((size_t)b * 128 + m0) * 512;
  const unsigned short* tkb = tkey + (size_t)b * 64 * 512;
  const unsigned short* skb = skey + ((size_t)b * 64 + sx * 2) * 512;
  if (tid < 128) *(uint4*)&skL[tid * 8] = *(const uint4*)&skb[tid * 8];
  const int srow = lane >> 3;
  const int scol = ((lane & 7) ^ srow) * 8;
#pragma unroll
  for (int h = 0; h < 2; ++h) {
    const int row = h * 32 + wv * 8;
    gload16(&qb[(size_t)(row + srow) * 512 + scol], &qS[0][row * 64]);
    gload16(&tkb[(size_t)(row + srow) * 512 + scol], &tkS[0][row * 64]);
  }
  const int cs0 = ((fq) ^ (fr & 7)) * 8;
  const int cs1 = ((4 + fq) ^ (fr & 7)) * 8;
  for (int kc = 0; kc < 8; ++kc) {
    const int cur = kc & 1;
    __syncthreads();  // drains prev prefetch (overlapped with prev compute)
    if (kc + 1 < 8) {
      const int k0 = (kc + 1) * 64;
      const int nxt = cur ^ 1;
#pragma unroll
      for (int h = 0; h < 2; ++h) {
        const int row = h * 32 + wv * 8;
        gload16(&qb[(size_t)(row + srow) * 512 + k0 + scol], &qS[nxt][row * 64]);
        gload16(&tkb[(size_t)(row + srow) * 512 + k0 + scol], &tkS[nxt][row * 64]);
      }
    }
#pragma unroll
    for (int ks = 0; ks < 2; ++ks) {
      const int cs = ks ? cs1 : cs0;
      short8_t a0 = *(const short8_t*)&qS[cur][(mw + fr) * 64 + cs];
      short8_t a1 = *(const short8_t*)&qS[cur][(mw + 16 + fr) * 64 + cs];
      uint4 tq[2];
      tq[0] = *(const uint4*)&tkS[cur][(nw + fr) * 64 + cs];
      tq[1] = *(const uint4*)&tkS[cur][(nw + 16 + fr) * 64 + cs];
      float tlo[2][4], thi[2][4];
#pragma unroll
      for (int h = 0; h < 2; ++h) {
        const unsigned* tw = (const unsigned*)&tq[h];
#pragma unroll
        for (int j = 0; j < 4; ++j) {
          tlo[h][j] = __uint_as_float(tw[j] << 16);
          thi[h][j] = __uint_as_float(tw[j] & 0xffff0000u);
        }
      }
      const int koff = kc * 64 + ks * 32 + fq * 8;  // logical k for sk (broadcast)
#pragma unroll
      for (int s = 0; s < 2; ++s) {
        uint4 skq = *(const uint4*)&skL[s * 512 + koff];
        const unsigned* sw = (const unsigned*)&skq;
        union { short8_t v; unsigned w[4]; } b0, b1;
#pragma unroll
        for (int j = 0; j < 4; ++j) {
          const float slo = __uint_as_float(sw[j] << 16);
          const float shi = __uint_as_float(sw[j] & 0xffff0000u);
          b0.w[j] = __builtin_amdgcn_perm(__float_as_uint(thi[0][j] * shi),
                                          __float_as_uint(tlo[0][j] * slo), 0x07060302);
          b1.w[j] = __builtin_amdgcn_perm(__float_as_uint(thi[1][j] * shi),
                                          __float_as_uint(tlo[1][j] * slo), 0x07060302);
        }
        acc[s][0] = MFMA16(a0, b0.v, acc[s][0]);
        acc[s][1] = MFMA16(a0, b1.v, acc[s][1]);
        acc[s][2] = MFMA16(a1, b0.v, acc[s][2]);
        acc[s][3] = MFMA16(a1, b1.v, acc[s][3]);
      }
    }
  }
#pragma unroll
  for (int s = 0; s < 2; ++s) {
    unsigned short* out = scores + ((size_t)b * 128 + m0) * 4096 + (size_t)(sx * 2 + s) * 64;
#pragma unroll
    for (int im = 0; im < 2; ++im)
#pragma unroll
      for (int jn = 0; jn < 2; ++jn) {
        f32x4_t aa = acc[s][im * 2 + jn];
        const int col = nw + jn * 16 + fr;
#pragma unroll
        for (int r = 0; r < 4; ++r) {
          const int row = mw + im * 16 + fq * 4 + r;
          out[(size_t)row * 4096 + col] = f2bf(aa[r]);
        }
      }
  }
}

// ---------- softmax: wave-per-row, registers only, no barriers ----------
__global__ __launch_bounds__(256) void k_softmax(unsigned short* __restrict__ s) {
  const int wv = threadIdx.x >> 6, lane = threadIdx.x & 63;
  unsigned short* p = s + ((size_t)blockIdx.x * 4 + wv) * 4096;
  uint4 v[8];
  float x[64];
#pragma unroll
  for (int c = 0; c < 8; ++c) v[c] = *(const uint4*)&p[c * 512 + lane * 8];
#pragma unroll
  for (int c = 0; c < 8; ++c) {
    const unsigned short* u = (const unsigned short*)&v[c];
#pragma unroll
    for (int j = 0; j < 8; ++j) x[c * 8 + j] = bf2f(u[j]);
  }
  float m = x[0];
#pragma unroll
  for (int j = 1; j < 64; ++j) m = fmaxf(m, x[j]);
#pragma unroll
  for (int off = 32; off > 0; off >>= 1) m = fmaxf(m, __shfl_xor(m, off));
  float sum = 0.f;
#pragma unroll
  for (int j = 0; j < 64; ++j) { x[j] = __expf(x[j] - m); sum += x[j]; }
#pragma unroll
  for (int off = 32; off > 0; off >>= 1) sum += __shfl_xor(sum, off);
  const float inv = 1.0f / sum;
#pragma unroll
  for (int c = 0; c < 8; ++c) {
    union { uint4 q; unsigned short u[8]; } o;
#pragma unroll
    for (int j = 0; j < 8; ++j) o.u[j] = f2bf(x[c * 8 + j] * inv);
    *(uint4*)&p[c * 512 + lane * 8] = o.q;
  }
}

// ---------- ctx partials: s-factored, no repack (R11 known-good) ----------
__global__ __launch_bounds__(256) void k_ctx(
    const unsigned short* __restrict__ p, const unsigned short* __restrict__ svT,
    const unsigned short* __restrict__ tvT, unsigned short* __restrict__ part) {
  const int b = blockIdx.x >> 1;
  const int m0 = (blockIdx.x & 1) * 64;
  const int n0 = blockIdx.y * 64;
  const int z = blockIdx.z;  // s-chunk: s in [z*16, z*16+16)
  FRAG_VARS;
  __shared__ __align__(16) unsigned short tvl[64 * 72];
  __shared__ __align__(16) unsigned short svl[64 * 24];
  {
    const unsigned short* tvb = tvT + (size_t)b * 32768 + (size_t)n0 * 64;
    const unsigned short* svb = svT + (size_t)b * 32768 + (size_t)n0 * 64 + z * 16;
#pragma unroll
    for (int it = 0; it < 2; ++it) {
      const int idx = tid + it * 256;
      const int r = idx >> 3, c = (idx & 7) * 8;
      *(uint4*)&tvl[r * 72 + c] = *(const uint4*)&tvb[(size_t)r * 64 + c];
    }
    if (tid < 128) {
      const int r = tid >> 1, c = (tid & 1) * 8;
      *(uint4*)&svl[r * 24 + c] = *(const uint4*)&svb[(size_t)r * 64 + c];
    }
  }
  __syncthreads();
  short8_t bv[2][2];
  bv[0][0] = *(const short8_t*)&tvl[(nw + fr) * 72 + fq * 8];
  bv[0][1] = *(const short8_t*)&tvl[(nw + fr) * 72 + 32 + fq * 8];
  bv[1][0] = *(const short8_t*)&tvl[(nw + 16 + fr) * 72 + fq * 8];
  bv[1][1] = *(const short8_t*)&tvl[(nw + 16 + fr) * 72 + 32 + fq * 8];
  const unsigned short* ar0 =
      p + ((size_t)b * 128 + m0 + mw + fr) * 4096 + z * 1024 + fq * 8;
  const unsigned short* ar1 = ar0 + (size_t)16 * 4096;
  uint4 pa[2][2][2];
#pragma unroll
  for (int d = 0; d < 2; ++d) {
    pa[d][0][0] = *(const uint4*)(ar0 + d * 64);
    pa[d][0][1] = *(const uint4*)(ar0 + d * 64 + 32);
    pa[d][1][0] = *(const uint4*)(ar1 + d * 64);
    pa[d][1][1] = *(const uint4*)(ar1 + d * 64 + 32);
  }
#pragma unroll 2
  for (int s = 0; s < 16; ++s) {
    const int sl = s & 1;
    short8_t a00 = __builtin_bit_cast(short8_t, pa[sl][0][0]);
    short8_t a01 = __builtin_bit_cast(short8_t, pa[sl][0][1]);
    short8_t a10 = __builtin_bit_cast(short8_t, pa[sl][1][0]);
    short8_t a11 = __builtin_bit_cast(short8_t, pa[sl][1][1]);
    if (s + 2 < 16) {
      const int off = (s + 2) * 64;
      pa[sl][0][0] = *(const uint4*)(ar0 + off);
      pa[sl][0][1] = *(const uint4*)(ar0 + off + 32);
      pa[sl][1][0] = *(const uint4*)(ar1 + off);
      pa[sl][1][1] = *(const uint4*)(ar1 + off + 32);
    }
    const f32x4_t z4 = {0.f, 0.f, 0.f, 0.f};
    f32x4_t M00 = MFMA16(a00, bv[0][0], z4);
    M00 = MFMA16(a01, bv[0][1], M00);
    f32x4_t M01 = MFMA16(a00, bv[1][0], z4);
    M01 = MFMA16(a01, bv[1][1], M01);
    f32x4_t M10 = MFMA16(a10, bv[0][0], z4);
    M10 = MFMA16(a11, bv[0][1], M10);
    f32x4_t M11 = MFMA16(a10, bv[1][0], z4);
    M11 = MFMA16(a11, bv[1][1], M11);
    const float sv0 = bf2f(svl[(nw + fr) * 24 + s]);
    const float sv1 = bf2f(svl[(nw + 16 + fr) * 24 + s]);
#pragma unroll
    for (int r = 0; r < 4; ++r) {
      acc00[r] += sv0 * M00[r];
      acc01[r] += sv1 * M01[r];
      acc10[r] += sv0 * M10[r];
      acc11[r] += sv1 * M11[r];
    }
  }
  unsigned short* out = part + ((size_t)z * 2048 + (size_t)b * 128 + m0) * 512 + n0;
  GEMM_EPILOGUE({ out[(size_t)ml * 512 + nl] = f2bf(vv); });
}

// ---------- reduce 4 bf16 partials -> bf16 ctx ----------
__global__ __launch_bounds__(256) void k_reduce(const unsigned short* __restrict__ part,
                                                unsigned short* __restrict__ ctx) {
  const size_t N = (size_t)2048 * 512;
  const size_t i = ((size_t)blockIdx.x * 256 + threadIdx.x) * 8;
  float s[8];
#pragma unroll
  for (int j = 0; j < 8; ++j) s[j] = 0.f;
#pragma unroll
  for (int z = 0; z < 4; ++z) {
    union { uint4 q; unsigned short u[8]; } t;
    t.q = *(const uint4*)&part[z * N + i];
#pragma unroll
    for (int j = 0; j < 8; ++j) s[j] += bf2f(t.u[j]);
  }
  union { uint4 q; unsigned short u[8]; } o;
#pragma unroll
  for (int j = 0; j < 8; ++j) o.u[j] = f2bf(s[j]);
  *(uint4*)&ctx[i] = o.q;
}

// ---------- out = relu(concat(query, ctx) @ Wo + bo): async dbuf, 12 x 128-k chunks ----------
__global__ __launch_bounds__(256) void k_out(
    const unsigned short* __restrict__ query, const unsigned short* __restrict__ ctx,
    const unsigned short* __restrict__ WoT, const unsigned short* __restrict__ bo,
    void* __restrict__ outv, const void* __restrict__ rawq) {
  __shared__ int shw[4];
  const int f32mode = detect_f32(rawq, threadIdx.x, shw);
  const int m0 = blockIdx.y * 64, n0 = blockIdx.x * 64;
  FRAG_VARS;
  __shared__ __align__(16) unsigned short sm[2][2][64 * 128];  // [buf][A/B] 64KB
  const int srow4 = lane >> 4;   // 0..3: row within 4-row gload window
  const int c8 = lane & 15;      // 16B-chunk column id
  // Issue one chunk (128 k-cols) of A and B into sm[buf]. Wave wv covers rows
  // wv*16..wv*16+15 in 4 windows of 4 rows; XOR chunk swizzle slot = c8^(row&7).
  auto issue = [&](int buf, int kc) {
    const unsigned short* abase;
    size_t astr;
    int kb;
    if (kc < 8) { abase = query + (size_t)m0 * 1024; astr = 1024; kb = kc * 128; }
    else { abase = ctx + (size_t)m0 * 512; astr = 512; kb = (kc - 8) * 128; }
#pragma unroll
    for (int g = 0; g < 4; ++g) {
      const int R0 = wv * 16 + g * 4;
      const int row = R0 + srow4;
      const int col = (c8 ^ ((g * 4 + srow4) & 7)) * 8;
      gload16(&abase[(size_t)row * astr + kb + col], &sm[buf][0][R0 * 128]);
      gload16(&WoT[(size_t)(n0 + row) * 1536 + kc * 128 + col], &sm[buf][1][R0 * 128]);
    }
  };
  issue(0, 0);
  for (int kc = 0; kc < 12; ++kc) {
    const int cur = kc & 1;
    __syncthreads();
    if (kc + 1 < 12) issue(cur ^ 1, kc + 1);
    const unsigned short* Ab = sm[cur][0];
    const unsigned short* Bb = sm[cur][1];
#pragma unroll
    for (int ks = 0; ks < 4; ++ks) {
      const int sl = ((ks * 4 + fq) ^ (fr & 7)) * 8;
      short8_t a0 = *(const short8_t*)&Ab[(mw + fr) * 128 + sl];
      short8_t a1 = *(const short8_t*)&Ab[(mw + 16 + fr) * 128 + sl];
      short8_t b0 = *(const short8_t*)&Bb[(nw + fr) * 128 + sl];
      short8_t b1 = *(const short8_t*)&Bb[(nw + 16 + fr) * 128 + sl];
      acc00 = MFMA16(a0, b0, acc00);
      acc01 = MFMA16(a0, b1, acc01);
      acc10 = MFMA16(a1, b0, acc10);
      acc11 = MFMA16(a1, b1, acc11);
    }
  }
  GEMM_EPILOGUE({
    float v = fmaxf(vv + bf2f(bo[n0 + nl]), 0.f);
    const size_t idx = (size_t)(m0 + ml) * 512 + n0 + nl;
    if (f32mode)
      ((float*)outv)[idx] = v;
    else
      ((unsigned short*)outv)[idx] = f2bf(v);
  });
}

// ---------- launch ----------
extern "C" void kernel_launch(void* const* d_in, const int* in_sizes, int n_in,
                              void* d_out, int out_size, void* d_ws, size_t ws_size,
                              hipStream_t stream) {
  const void* query = d_in[0];
  const void* src = d_in[1];
  const void* trg = d_in[2];
  const void* Wq = d_in[3];
  const void* bq = d_in[4];
  const void* Ws = d_in[5];
  const void* bs = d_in[6];
  const void* Wt = d_in[7];
  const void* bt = d_in[8];
  const void* Wsv = d_in[9];
  const void* bsv = d_in[10];
  const void* Wtv = d_in[11];
  const void* btv = d_in[12];
  const void* Wo = d_in[13];
  const void* bo = d_in[14];

  char* ws = (char*)d_ws;
  size_t off = 0;
  auto alloc = [&](size_t bytes) {
    char* ptr = ws + off;
    off = (off + bytes + 255) & ~(size_t)255;
    return ptr;
  };
  unsigned short* qc = (unsigned short*)alloc((size_t)2048 * 1024 * 2);
  unsigned short* srcc = (unsigned short*)alloc((size_t)1024 * 1024 * 2);
  unsigned short* trgc = (unsigned short*)alloc((size_t)1024 * 1024 * 2);
  unsigned short* biasc = (unsigned short*)alloc((size_t)6 * 512 * 2);
  unsigned short* wT = (unsigned short*)alloc((size_t)5 * 524288 * 2);
  unsigned short* woT = (unsigned short*)alloc((size_t)512 * 1536 * 2);
  unsigned short* q_s = (unsigned short*)alloc((size_t)2048 * 512 * 2);
  unsigned short* s_key = (unsigned short*)alloc((size_t)1024 * 512 * 2);
  unsigned short* t_key = (unsigned short*)alloc((size_t)1024 * 512 * 2);
  unsigned short* sv_T = (unsigned short*)alloc((size_t)16 * 512 * 64 * 2);
  unsigned short* tv_T = (unsigned short*)alloc((size_t)16 * 512 * 64 * 2);
  unsigned short* scores = (unsigned short*)alloc((size_t)2048 * 4096 * 2);
  unsigned short* part = (unsigned short*)alloc((size_t)4 * 2048 * 512 * 2);
  unsigned short* ctx = (unsigned short*)alloc((size_t)2048 * 512 * 2);
  (void)ws_size; (void)in_sizes; (void)n_in; (void)out_size;

  PrepArgs pr;
  pr.csrc[0] = query; pr.csrc[1] = src; pr.csrc[2] = trg;
  pr.csrc[3] = bq; pr.csrc[4] = bs; pr.csrc[5] = bt;
  pr.csrc[6] = bsv; pr.csrc[7] = btv; pr.csrc[8] = bo;
  pr.cdst[0] = qc; pr.cdst[1] = srcc; pr.cdst[2] = trgc;
  for (int i = 0; i < 6; ++i) pr.cdst[3 + i] = biasc + i * 512;
  pr.cn[0] = 2048 * 1024; pr.cn[1] = 1024 * 1024; pr.cn[2] = 1024 * 1024;
  for (int i = 0; i < 6; ++i) pr.cn[3 + i] = 512;
  pr.tsrc[0] = Wq; pr.tsrc[1] = Ws; pr.tsrc[2] = Wt;
  pr.tsrc[3] = Wsv; pr.tsrc[4] = Wtv; pr.tsrc[5] = Wo;
  for (int i = 0; i < 5; ++i) { pr.tdst[i] = wT + (size_t)i * 524288; pr.tK[i] = 1024; }
  pr.tdst[5] = woT; pr.tK[5] = 1536;
  hipLaunchKernelGGL(k_prep, dim3(16, 48, 15), dim3(256), 0, stream, pr);

  ProjArgs pa;
  pa.A[0] = qc; pa.A[1] = srcc; pa.A[2] = trgc; pa.A[3] = srcc; pa.A[4] = trgc;
  for (int i = 0; i < 5; ++i) pa.W[i] = wT + (size_t)i * 524288;
  for (int i = 0; i < 5; ++i) pa.bias[i] = biasc + i * 512;
  pa.out[0] = q_s; pa.out[1] = s_key; pa.out[2] = t_key; pa.out[3] = sv_T; pa.out[4] = tv_T;
  hipLaunchKernelGGL(k_proj, dim3(768), dim3(256), 0, stream, pa);

  hipLaunchKernelGGL(k_scores, dim3(32, 2, 16), dim3(256), 0, stream, q_s, s_key, t_key, scores);
  hipLaunchKernelGGL(k_softmax, dim3(512), dim3(256), 0, stream, scores);
  hipLaunchKernelGGL(k_ctx, dim3(32, 8, 4), dim3(256), 0, stream, scores, sv_T, tv_T, part);
  hipLaunchKernelGGL(k_reduce, dim3(512), dim3(256), 0, stream, part, ctx);
  hipLaunchKernelGGL(k_out, dim3(8, 32, 1), dim3(256), 0, stream, qc, ctx, woT,
                     biasc + 5 * 512, d_out, query);
}